// Round 3
// baseline (299.773 us; speedup 1.0000x reference)
//
#include <hip/hip_runtime.h>
#include <stdint.h>

typedef float f32x4 __attribute__((ext_vector_type(4)));
typedef short bf16x8 __attribute__((ext_vector_type(8)));
typedef short bf16x4 __attribute__((ext_vector_type(4)));

__device__ __forceinline__ float bf2f(unsigned short h){
  union { unsigned int u; float f; } v; v.u = ((unsigned int)h) << 16; return v.f;
}
__device__ __forceinline__ unsigned short f2bf(float f){
  union { float f; unsigned int u; } v; v.f = f;
  return (unsigned short)((v.u + 0x7fffu + ((v.u >> 16) & 1u)) >> 16);
}

typedef __attribute__((address_space(1))) const unsigned int ga_u32;
typedef __attribute__((address_space(3))) unsigned int ls_u32;
__device__ __forceinline__ void async_load16(const void* g, void* l){
  __builtin_amdgcn_global_load_lds((ga_u32*)g, (ls_u32*)l, 16, 0, 0);
}

#define CFENCE() asm volatile("" ::: "memory")

// ---------------------------------------------------------------------------
// prep: fp32 weights -> bf16 (5 x 512x512), biases -> packed fp32 [5][512]
__global__ __launch_bounds__(256) void k_prep_w(
    const float* __restrict__ w0, const float* __restrict__ w1,
    const float* __restrict__ w2, const float* __restrict__ w3,
    const float* __restrict__ w4, unsigned short* __restrict__ out)
{
  int i = blockIdx.x * 256 + threadIdx.x;
  const float* w = (blockIdx.y == 0) ? w0 : (blockIdx.y == 1) ? w1 :
                   (blockIdx.y == 2) ? w2 : (blockIdx.y == 3) ? w3 : w4;
  out[(size_t)blockIdx.y * 262144 + i] = f2bf(w[i]);
}
__global__ __launch_bounds__(256) void k_prep_b(
    const float* __restrict__ b0, const float* __restrict__ b1,
    const float* __restrict__ b2, const float* __restrict__ b3,
    const float* __restrict__ b4, float* __restrict__ out)
{
  int i = blockIdx.x * 256 + threadIdx.x;   // 0..2559
  int s = i >> 9, r = i & 511;
  const float* b = (s == 0) ? b0 : (s == 1) ? b1 : (s == 2) ? b2 : (s == 3) ? b3 : b4;
  out[i] = b[r];
}

// ---------------------------------------------------------------------------
// build xs_bf[b][l][c] = bf16( x[b][c][l] + pos[l][c] )
__global__ __launch_bounds__(256) void k_build_xs(
    const float* __restrict__ x, const float* __restrict__ pos,
    unsigned short* __restrict__ xsb)
{
  __shared__ float tile[64][65];
  const int lt = blockIdx.x, ct = blockIdx.y, b = blockIdx.z;
  const int t = threadIdx.x;
  const int rr = t >> 3, c8 = (t & 7) * 8;
  #pragma unroll
  for (int pass = 0; pass < 2; pass++){
    int r = rr + pass * 32;
    const float* src = x + ((size_t)b * 512 + ct*64 + r) * 4096 + lt*64 + c8;
    f32x4 v0 = *(const f32x4*)src;
    f32x4 v1 = *(const f32x4*)(src + 4);
    #pragma unroll
    for (int s = 0; s < 4; s++){ tile[r][c8+s] = v0[s]; tile[r][c8+4+s] = v1[s]; }
  }
  __syncthreads();
  #pragma unroll
  for (int pass = 0; pass < 2; pass++){
    int ll = rr + pass * 32;
    int gl = lt*64 + ll;
    const float* pp = pos + (size_t)gl * 512 + ct*64 + c8;
    bf16x8 hv;
    #pragma unroll
    for (int s = 0; s < 8; s++)
      hv[s] = (short)f2bf(tile[c8+s][ll] + pp[s]);
    *(bf16x8*)(xsb + ((size_t)b * 4096 + gl) * 512 + ct*64 + c8) = hv;
  }
}

// ---------------------------------------------------------------------------
// generic bf16 transpose: in[z][R][C] -> out[z][C][R]   (used for mid only)
__global__ __launch_bounds__(256) void k_transpose_bf(
    const unsigned short* __restrict__ in, unsigned short* __restrict__ out,
    int R, int C)
{
  __shared__ float tile[64][65];
  const int rt = blockIdx.x, ct = blockIdx.y, z = blockIdx.z;
  const unsigned short* src = in  + (size_t)z * R * C;
  unsigned short*       dst = out + (size_t)z * R * C;
  const int t = threadIdx.x;
  const int rr = t >> 3, c8 = (t & 7) * 8;
  #pragma unroll
  for (int pass = 0; pass < 2; pass++){
    int r = rr + pass * 32;
    bf16x8 v = *(const bf16x8*)(src + (size_t)(rt*64 + r) * C + ct*64 + c8);
    #pragma unroll
    for (int s = 0; s < 8; s++) tile[r][c8+s] = bf2f((unsigned short)v[s]);
  }
  __syncthreads();
  #pragma unroll
  for (int pass = 0; pass < 2; pass++){
    int c = rr + pass * 32;
    bf16x8 hv;
    #pragma unroll
    for (int s = 0; s < 8; s++) hv[s] = (short)f2bf(tile[c8+s][c]);
    *(bf16x8*)(dst + (size_t)(ct*64 + c) * R + rt*64 + c8) = hv;
  }
}

// ---------------------------------------------------------------------------
// diagKV[b][c] = sum_l K*V ; Ksum[b][c] = sum_l K
__global__ __launch_bounds__(256) void k_reduce_kv(
    const unsigned short* __restrict__ Kb, const unsigned short* __restrict__ Vb,
    float* __restrict__ diag, float* __restrict__ ksum)
{
  const int c0 = blockIdx.x * 64, b = blockIdx.y, lz = blockIdx.z * 512;
  const int t = threadIdx.x;
  const int c = c0 + (t & 63), lo = t >> 6;
  float d = 0.f, s = 0.f;
  for (int l = lo; l < 512; l += 4){
    size_t idx = ((size_t)b * 4096 + lz + l) * 512 + c;
    float kk = bf2f(Kb[idx]);
    float vv = bf2f(Vb[idx]);
    d += kk * vv; s += kk;
  }
  __shared__ float sd[256], sk[256];
  sd[t] = d; sk[t] = s;
  __syncthreads();
  if (t < 64){
    d = sd[t] + sd[t+64] + sd[t+128] + sd[t+192];
    s = sk[t] + sk[t+64] + sk[t+128] + sk[t+192];
    atomicAdd(&diag[b*512 + c0 + t], d);
    atomicAdd(&ksum[b*512 + c0 + t], s);
  }
}

// ---------------------------------------------------------------------------
// per row: Z = 1/sum_c Q*(Ksum+eps); r0 = Q*diagKV*Z  (bf16 out)
__global__ __launch_bounds__(256) void k_z_r0(
    const unsigned short* __restrict__ Qb, const float* __restrict__ ksum,
    const float* __restrict__ diag, unsigned short* __restrict__ r0)
{
  const int row = blockIdx.x * 4 + (threadIdx.x >> 6);
  const int lane = threadIdx.x & 63;
  const int b = row >> 12;
  bf16x8 q = *(const bf16x8*)(Qb + (size_t)row * 512 + lane * 8);
  float qf[8];
  #pragma unroll
  for (int s = 0; s < 8; s++) qf[s] = bf2f((unsigned short)q[s]);
  f32x4 k0 = *(const f32x4*)(ksum + b*512 + lane*8);
  f32x4 k1 = *(const f32x4*)(ksum + b*512 + lane*8 + 4);
  f32x4 d0 = *(const f32x4*)(diag + b*512 + lane*8);
  f32x4 d1 = *(const f32x4*)(diag + b*512 + lane*8 + 4);
  float den = 0.f;
  #pragma unroll
  for (int s = 0; s < 4; s++) den += qf[s]   * (k0[s] + 1e-6f);
  #pragma unroll
  for (int s = 0; s < 4; s++) den += qf[4+s] * (k1[s] + 1e-6f);
  #pragma unroll
  for (int m = 1; m < 64; m <<= 1) den += __shfl_xor(den, m);
  float Z = 1.0f / den;
  bf16x8 hv;
  #pragma unroll
  for (int s = 0; s < 4; s++) hv[s]   = (short)f2bf(qf[s]   * d0[s] * Z);
  #pragma unroll
  for (int s = 0; s < 4; s++) hv[4+s] = (short)f2bf(qf[4+s] * d1[s] * Z);
  *(bf16x8*)(r0 + (size_t)row * 512 + lane * 8) = hv;
}

// ---------------------------------------------------------------------------
// row softmax: S[row][0..511] fp32 -> mid bf16
__global__ __launch_bounds__(64) void k_softmax(
    const float* __restrict__ S, unsigned short* __restrict__ mid)
{
  const size_t row = blockIdx.x;
  const int lane = threadIdx.x;
  const float* p = S + row * 512 + lane * 8;
  f32x4 v0 = *(const f32x4*)p, v1 = *(const f32x4*)(p + 4);
  float mx = v0[0];
  #pragma unroll
  for (int s = 1; s < 4; s++) mx = fmaxf(mx, v0[s]);
  #pragma unroll
  for (int s = 0; s < 4; s++) mx = fmaxf(mx, v1[s]);
  #pragma unroll
  for (int m = 1; m < 64; m <<= 1) mx = fmaxf(mx, __shfl_xor(mx, m));
  float e[8]; float sum = 0.f;
  #pragma unroll
  for (int s = 0; s < 4; s++){ e[s]   = __expf(v0[s] - mx); sum += e[s]; }
  #pragma unroll
  for (int s = 0; s < 4; s++){ e[4+s] = __expf(v1[s] - mx); sum += e[4+s]; }
  #pragma unroll
  for (int m = 1; m < 64; m <<= 1) sum += __shfl_xor(sum, m);
  float inv = 1.0f / sum;
  bf16x8 hv;
  #pragma unroll
  for (int s = 0; s < 8; s++) hv[s] = (short)f2bf(e[s] * inv);
  *(bf16x8*)(mid + row * 512 + lane * 8) = hv;
}

// ===========================================================================
// OLD 128x128 2-phase GEMM (kept for mid-logits GEMM only; 128 blocks)
// ===========================================================================
#define GEMM_PRE()                                                            \
  const int tid = threadIdx.x;                                                \
  const int lane = tid & 63;                                                  \
  const int wave = tid >> 6;                                                  \
  const int wm = wave >> 1, wn = wave & 1;                                    \
  size_t aoff[4], boff[4]; int ldsq[4];                                       \
  _Pragma("unroll")                                                           \
  for (int i = 0; i < 4; i++){                                                \
    int qq = i*4 + wave;                                                      \
    int ch = qq*64 + lane;                                                    \
    int m  = ch >> 3, p = ch & 7;                                             \
    int lc = p ^ (m & 7);                                                     \
    aoff[i] = (size_t)(m0 + m) * K + lc*8;                                    \
    boff[i] = (size_t)(n0 + m) * K + lc*8;                                    \
    ldsq[i] = qq * 1024;                                                      \
  }                                                                           \
  f32x4 acc[4][4];                                                            \
  const f32x4 vzero = {0.f,0.f,0.f,0.f};                                      \
  _Pragma("unroll")                                                           \
  for (int i = 0; i < 4; i++)                                                 \
    _Pragma("unroll")                                                         \
    for (int j = 0; j < 4; j++) acc[i][j] = vzero;                            \
  int arow[4], brow[4];                                                       \
  _Pragma("unroll")                                                           \
  for (int f = 0; f < 4; f++){                                                \
    arow[f] = (wm*64 + f*16 + (lane & 15)) * 64;                              \
    brow[f] = (wn*64 + f*16 + (lane & 15)) * 64;                              \
  }                                                                           \
  const int kg = lane >> 4;                                                   \
  const int l7 = lane & 7;

#define GEMM_STAGE(buf, kt)                                                   \
  _Pragma("unroll")                                                           \
  for (int i = 0; i < 4; i++){                                                \
    async_load16(Ae + aoff[i] + (kt)*64, (char*)&smem[(buf)*8192] + ldsq[i]); \
    async_load16(Be + boff[i] + (kt)*64, (char*)&smem[16384 + (buf)*8192] + ldsq[i]); \
  }

#define GEMM_COMPUTE(buf)                                                     \
  _Pragma("unroll")                                                           \
  for (int ks = 0; ks < 2; ks++){                                             \
    bf16x8 a[4], b[4];                                                        \
    const int pa = (ks*4 + kg) ^ l7;                                          \
    _Pragma("unroll")                                                         \
    for (int f = 0; f < 4; f++){                                              \
      a[f] = *(const bf16x8*)&smem[(buf)*8192 + arow[f] + pa*8];              \
      b[f] = *(const bf16x8*)&smem[16384 + (buf)*8192 + brow[f] + pa*8];      \
    }                                                                         \
    _Pragma("unroll")                                                         \
    for (int i = 0; i < 4; i++)                                               \
      _Pragma("unroll")                                                       \
      for (int j = 0; j < 4; j++)                                             \
        acc[i][j] = __builtin_amdgcn_mfma_f32_16x16x32_bf16(a[i], b[j], acc[i][j], 0, 0, 0); \
  }

#define GEMM_KLOOP(nkt)                                                       \
  GEMM_STAGE(0, 0);                                                           \
  __syncthreads();                                                            \
  int cur = 0;                                                                \
  for (int kt = 0; kt < (nkt); kt++){                                         \
    if (kt + 1 < (nkt)) { GEMM_STAGE(cur ^ 1, kt + 1); }                      \
    GEMM_COMPUTE(cur);                                                        \
    __syncthreads();                                                          \
    cur ^= 1;                                                                 \
  }

// mid logits: S[b][i][j] = sum_l Q1T[b,i,l] * K1T[b,j,l]  (K=4096)
__global__ __launch_bounds__(256) void gemm_mid(
    const unsigned short* __restrict__ A,
    const unsigned short* __restrict__ Bt,
    float* __restrict__ outf, int K)
{
  __shared__ unsigned short smem[32768];
  const int bid = blockIdx.x;
  const int cpx = gridDim.x >> 3;
  const int wgid = (bid & 7) * cpx + (bid >> 3);
  const int z = wgid >> 4;
  const int mtile = (wgid >> 2) & 3, ntile = wgid & 3;
  const int m0 = mtile * 128, n0 = ntile * 128;
  const unsigned short* Ae = A  + (size_t)z * 512 * (size_t)K;
  const unsigned short* Be = Bt + (size_t)z * 512 * (size_t)K;

  GEMM_PRE();
  GEMM_KLOOP(K >> 6);

  const int lr = lane >> 4;
  const int lc16 = lane & 15;
  #pragma unroll
  for (int j = 0; j < 4; j++){
    int cidx = n0 + wn*64 + j*16 + lc16;
    #pragma unroll
    for (int i = 0; i < 4; i++){
      int r = m0 + wm*64 + i*16 + lr*4;
      #pragma unroll
      for (int q = 0; q < 4; q++)
        outf[(size_t)z * 262144 + (size_t)(r + q) * 512 + cidx] = acc[i][j][q];
    }
  }
}

// ===========================================================================
// NEW: 256x256-tile, 8-wave, 8-phase counted-vmcnt GEMM (T2+T3+T4+T5).
// BK=64, 2 dbuf, LDS 128KB. A row-major [M][512], Bt row-major [N][512].
// LDS ushort map: A: d*16384 + h*8192 + row_local*64 + chunk*8   (h = half)
//                 B: 32768 + same.
// Swizzle: global source k-chunk pre-XORed by (row&7); reads XOR back.
// Phase ledger (iteration it computes K-tiles 2it [dbuf0] and 2it+1 [dbuf1]):
//   ph0: rd A0.mh0 + B0.np0  | stage A[1][0]<-t(2it+1)
//   ph1: rd B0.np1           | stage A[1][1]<-t(2it+1)
//   ph2: rd A0.mh1           | stage B[0][0]<-t(2it+2)
//   ph3: (regs)              | stage A[0][0]<-t(2it+2) | vmcnt(4)
//   ph4: rd A1.mh0 + B1.np0  | stage A[0][1]<-t(2it+2)
//   ph5: rd B1.np1           | stage B[0][1]<-t(2it+2)
//   ph6: rd A1.mh1           | stage B[1][0]<-t(2it+3)
//   ph7: (regs)              | stage B[1][1]<-t(2it+3) | vmcnt(4)
// Every stage target's last read is >=1 barrier earlier; vmcnt(4) leaves the
// youngest 2 halves (4 loads) in flight. Last iteration: no t+2/t+3 stages,
// vmcnt(0) at ph3, none at ph7.
// ===========================================================================

#define G8_PRE(AE, BE, N0ABS)                                                 \
  const int t = threadIdx.x;                                                  \
  const int lane = t & 63;                                                    \
  const int wave = t >> 6;                                                    \
  const int wm = wave >> 2, wn = wave & 3;                                    \
  const int l15 = lane & 15, kg = lane >> 4;                                  \
  const int lcw = ((t & 7) ^ ((t >> 3) & 7)) * 8;                             \
  const unsigned short* a_src = (AE) + (size_t)(m0 + (t >> 3)) * 512 + lcw;   \
  const unsigned short* b_src = (BE) + (size_t)((N0ABS) + (t >> 3)) * 512 + lcw; \
  f32x4 acc[8][4];                                                            \
  const f32x4 vzero = {0.f,0.f,0.f,0.f};                                      \
  _Pragma("unroll")                                                           \
  for (int i = 0; i < 8; i++)                                                 \
    _Pragma("unroll")                                                         \
    for (int j = 0; j < 4; j++) acc[i][j] = vzero;                            \
  bf16x8 af[4][2], bf[4][2];

#define STAGE_A(D,H,TT) do{                                                   \
  async_load16(a_src + (H)*65536 + (TT)*64,                                   \
               (char*)smem + ((D)*16384 + (H)*8192 + t*8)*2);                 \
  async_load16(a_src + (H)*65536 + 32768 + (TT)*64,                           \
               (char*)smem + ((D)*16384 + (H)*8192 + 4096 + t*8)*2);          \
}while(0)

#define STAGE_B(D,H,TT) do{                                                   \
  async_load16(b_src + (H)*65536 + (TT)*64,                                   \
               (char*)smem + (32768 + (D)*16384 + (H)*8192 + t*8)*2);         \
  async_load16(b_src + (H)*65536 + 32768 + (TT)*64,                           \
               (char*)smem + (32768 + (D)*16384 + (H)*8192 + 4096 + t*8)*2);  \
}while(0)

#define READ_A(D, MH) do{                                                     \
  _Pragma("unroll")                                                           \
  for (int mfl = 0; mfl < 4; ++mfl){                                          \
    const int rl = ((MH)*4 + mfl)*16 + l15;                                   \
    _Pragma("unroll")                                                         \
    for (int ks = 0; ks < 2; ++ks){                                           \
      const int ck = (ks*4 + kg) ^ (rl & 7);                                  \
      af[mfl][ks] = *(const bf16x8*)&smem[(D)*16384 + wm*8192 + rl*64 + ck*8];\
    }                                                                         \
  }                                                                           \
}while(0)

#define READ_B(D, NP) do{                                                     \
  _Pragma("unroll")                                                           \
  for (int nfl = 0; nfl < 2; ++nfl){                                          \
    const int nf = (NP)*2 + nfl;                                              \
    const int rbl = (wn & 1)*64 + nf*16 + l15;                                \
    _Pragma("unroll")                                                         \
    for (int ks = 0; ks < 2; ++ks){                                           \
      const int ck = (ks*4 + kg) ^ (rbl & 7);                                 \
      bf[nf][ks] = *(const bf16x8*)&smem[32768 + (D)*16384 + (wn>>1)*8192 + rbl*64 + ck*8]; \
    }                                                                         \
  }                                                                           \
}while(0)

#define QUAD(MH, NP)                                                          \
  _Pragma("unroll")                                                           \
  for (int mfl = 0; mfl < 4; ++mfl)                                           \
    _Pragma("unroll")                                                         \
    for (int nfl = 0; nfl < 2; ++nfl)                                         \
      _Pragma("unroll")                                                       \
      for (int ks = 0; ks < 2; ++ks)                                          \
        acc[(MH)*4+mfl][(NP)*2+nfl] = __builtin_amdgcn_mfma_f32_16x16x32_bf16(\
            af[mfl][ks], bf[(NP)*2+nfl][ks], acc[(MH)*4+mfl][(NP)*2+nfl], 0,0,0);

#define PH_MID()  CFENCE(); __builtin_amdgcn_s_barrier(); __builtin_amdgcn_s_setprio(1)
#define PH_END()  __builtin_amdgcn_s_setprio(0); CFENCE(); __builtin_amdgcn_s_barrier(); CFENCE()
#define PH_END_VM4() __builtin_amdgcn_s_setprio(0);                           \
  asm volatile("s_waitcnt vmcnt(4)" ::: "memory");                            \
  __builtin_amdgcn_s_barrier(); CFENCE()
#define PH_END_VM0() __builtin_amdgcn_s_setprio(0);                           \
  asm volatile("s_waitcnt vmcnt(0)" ::: "memory");                            \
  __builtin_amdgcn_s_barrier(); CFENCE()

// K = 512 fixed -> nkt = 8, niter = 4 (>=2 required)
#define G8_KLOOP()                                                            \
  STAGE_A(0,0,0); STAGE_A(0,1,0); STAGE_B(0,0,0); STAGE_B(0,1,0);             \
  STAGE_B(1,0,1); STAGE_B(1,1,1);                                             \
  asm volatile("s_waitcnt vmcnt(4)" ::: "memory");                            \
  __builtin_amdgcn_s_barrier(); CFENCE();                                     \
  for (int it = 0; it < 3; ++it){                                             \
    const int t1 = 2*it + 1, t2 = 2*it + 2, t3 = 2*it + 3;                    \
    READ_A(0,0); READ_B(0,0); STAGE_A(1,0,t1);                                \
    PH_MID(); QUAD(0,0); PH_END();                                            \
    READ_B(0,1); STAGE_A(1,1,t1);                                             \
    PH_MID(); QUAD(0,1); PH_END();                                            \
    READ_A(0,1); STAGE_B(0,0,t2);                                             \
    PH_MID(); QUAD(1,0); PH_END();                                            \
    STAGE_A(0,0,t2);                                                          \
    PH_MID(); QUAD(1,1); PH_END_VM4();                                        \
    READ_A(1,0); READ_B(1,0); STAGE_A(0,1,t2);                                \
    PH_MID(); QUAD(0,0); PH_END();                                            \
    READ_B(1,1); STAGE_B(0,1,t2);                                             \
    PH_MID(); QUAD(0,1); PH_END();                                            \
    READ_A(1,1); STAGE_B(1,0,t3);                                             \
    PH_MID(); QUAD(1,0); PH_END();                                            \
    STAGE_B(1,1,t3);                                                          \
    PH_MID(); QUAD(1,1); PH_END_VM4();                                        \
  }                                                                           \
  { /* last iteration: tiles 6 (dbuf0), 7 (dbuf1); no t+2/t+3 stages */       \
    READ_A(0,0); READ_B(0,0); STAGE_A(1,0,7);                                 \
    PH_MID(); QUAD(0,0); PH_END();                                            \
    READ_B(0,1); STAGE_A(1,1,7);                                              \
    PH_MID(); QUAD(0,1); PH_END();                                            \
    READ_A(0,1);                                                              \
    PH_MID(); QUAD(1,0); PH_END();                                            \
    PH_MID(); QUAD(1,1); PH_END_VM0();                                        \
    READ_A(1,0); READ_B(1,0);                                                 \
    PH_MID(); QUAD(0,0); PH_END();                                            \
    READ_B(1,1);                                                              \
    PH_MID(); QUAD(0,1); PH_END();                                            \
    READ_A(1,1);                                                              \
    PH_MID(); QUAD(1,0); PH_END();                                            \
    PH_MID(); QUAD(1,1); PH_END();                                            \
  }

// ---------------------------------------------------------------------------
// fused 5-projection 8-phase GEMM. grid = 1280 x 512 threads.
// wgid = mtile*10 + nslot; nslot: slot = nslot>>1 (Q,K,V,Q1,K1), ncol = nslot&1.
__global__ __launch_bounds__(512, 2) void gemm8_proj(
    const unsigned short* __restrict__ A,
    const unsigned short* __restrict__ W,
    const float* __restrict__ bias5,
    unsigned short* __restrict__ Qb, unsigned short* __restrict__ Kb,
    unsigned short* __restrict__ Vb, unsigned short* __restrict__ Q1T,
    unsigned short* __restrict__ K1T)
{
  __shared__ unsigned short smem[65536];   // 128KB
  const int bid = blockIdx.x;
  const int wgid = (bid & 7) * 160 + (bid >> 3);   // 1280 % 8 == 0: bijective
  const int mtile = wgid / 10;
  const int nslot = wgid % 10;
  const int slot = nslot >> 1;
  const int ncol = nslot & 1;
  const int m0 = mtile * 256;
  const int nc0 = ncol * 256;

  G8_PRE(A, W + (size_t)slot * 262144, nc0);
  G8_KLOOP();

  const int lr4 = kg;      // C/D: col = lane&15, row = lr4*4 + q
  if (slot < 3){
    unsigned short* o = (slot == 0) ? Qb : (slot == 1) ? Kb : Vb;
    const bool relu = (slot < 2);
    #pragma unroll
    for (int nf = 0; nf < 4; nf++){
      int col = nc0 + wn*64 + nf*16 + l15;
      float bb = bias5[slot*512 + col];
      #pragma unroll
      for (int mf = 0; mf < 8; mf++){
        int r = m0 + wm*128 + mf*16 + lr4*4;
        #pragma unroll
        for (int q = 0; q < 4; q++){
          float v = acc[mf][nf][q] + bb;
          if (relu) v = v > 0.f ? v : 0.f;
          o[(size_t)(r + q) * 512 + col] = f2bf(v);
        }
      }
    }
  } else {
    // transposed output via in-LDS 256x256 transpose (chunk-XOR swizzled)
    unsigned short* o = (slot == 3) ? Q1T : K1T;
    const int b = mtile >> 4;
    const int l0 = (mtile & 15) * 256;
    __syncthreads();
    #pragma unroll
    for (int nf = 0; nf < 4; nf++){
      int cl_ = wn*64 + nf*16 + l15;
      float bb = bias5[slot*512 + nc0 + cl_];
      #pragma unroll
      for (int mf = 0; mf < 8; mf++){
        #pragma unroll
        for (int q = 0; q < 4; q++){
          int ll = wm*128 + mf*16 + lr4*4 + q;
          int sw = ((ll >> 3) ^ (cl_ & 7)) * 8 + (ll & 7);
          smem[cl_*256 + sw] = f2bf(acc[mf][nf][q] + bb);
        }
      }
    }
    __syncthreads();
    #pragma unroll
    for (int rep = 0; rep < 16; rep++){
      int c = rep*16 + (t >> 5);
      int lch = t & 31;
      bf16x8 v = *(const bf16x8*)&smem[c*256 + (lch ^ (c & 7))*8];
      *(bf16x8*)(o + ((size_t)b*512 + nc0 + c)*4096 + l0 + lch*8) = v;
    }
  }
}

// ---------------------------------------------------------------------------
// result 8-phase GEMM: y = xs + gamma*(r0 @ midT^T) in-place + BN stats.
// grid = 256 x 512 threads. wgid = mtile*2 + ntile.
__global__ __launch_bounds__(512, 2) void gemm8_res(
    const unsigned short* __restrict__ A,        // r0 [32768][512]
    const unsigned short* __restrict__ Bt,       // midT [8][512][512]
    unsigned short* __restrict__ outh,           // xs bf16, in-place -> y
    const float* __restrict__ gamma_p,
    float* __restrict__ bnS, float* __restrict__ bnQ)
{
  __shared__ unsigned short smem[65536];
  const int bid = blockIdx.x;
  const int wgid = (bid & 7) * 32 + (bid >> 3);   // 256 % 8 == 0
  const int mtile = wgid >> 1;
  const int ntile = wgid & 1;
  const int m0 = mtile * 256;
  const int nc0 = ntile * 256;

  G8_PRE(A, Bt + (size_t)(mtile >> 4) * 262144, nc0);
  G8_KLOOP();

  const int lr4 = kg;
  float g = gamma_p[0];
  float sc[4] = {0.f,0.f,0.f,0.f}, sq[4] = {0.f,0.f,0.f,0.f};
  #pragma unroll
  for (int nf = 0; nf < 4; nf++){
    int col = nc0 + wn*64 + nf*16 + l15;
    #pragma unroll
    for (int mf = 0; mf < 8; mf++){
      int r = m0 + wm*128 + mf*16 + lr4*4;
      #pragma unroll
      for (int q = 0; q < 4; q++){
        size_t idx = (size_t)(r + q) * 512 + col;
        float y = bf2f(outh[idx]) + g * acc[mf][nf][q];
        outh[idx] = f2bf(y);
        sc[nf] += y; sq[nf] += y * y;
      }
    }
  }
  // reduce per-col within wave (lanes 16/32/48 hold same col, other rows)
  #pragma unroll
  for (int nf = 0; nf < 4; nf++){
    #pragma unroll
    for (int m = 16; m < 64; m <<= 1){
      sc[nf] += __shfl_xor(sc[nf], m);
      sq[nf] += __shfl_xor(sq[nf], m);
    }
  }
  __syncthreads();
  float* sS = (float*)(void*)smem;   // 256 floats
  float* sQ = sS + 256;
  if (t < 512) ((float*)(void*)smem)[t] = 0.f;
  __syncthreads();
  if (lane < 16){
    #pragma unroll
    for (int nf = 0; nf < 4; nf++){
      atomicAdd(&sS[wn*64 + nf*16 + lane], sc[nf]);
      atomicAdd(&sQ[wn*64 + nf*16 + lane], sq[nf]);
    }
  }
  __syncthreads();
  if (t < 256){
    atomicAdd(&bnS[nc0 + t], sS[t]);
    atomicAdd(&bnQ[nc0 + t], sQ[t]);
  }
}

// ---------------------------------------------------------------------------
// finalize: y[b][l][c] bf16 -> out[b][c][l] fp32, BN affine + relu
__global__ __launch_bounds__(256) void k_bn_finalize(
    const unsigned short* __restrict__ y, const float* __restrict__ bnS,
    const float* __restrict__ bnQ, const float* __restrict__ bnw,
    const float* __restrict__ bnb, float* __restrict__ out)
{
  __shared__ float tile[64][65];
  __shared__ float scale_s[64], shift_s[64];
  const int lt = blockIdx.x, ct = blockIdx.y, b = blockIdx.z;
  const int t = threadIdx.x;
  if (t < 64){
    int c = ct*64 + t;
    float s = bnS[c], q = bnQ[c];
    float mean = s * (1.0f / 32768.0f);
    float var  = q * (1.0f / 32768.0f) - mean * mean;
    float inv  = rsqrtf(var + 1e-5f);
    float scv  = bnw[c] * inv;
    scale_s[t] = scv;
    shift_s[t] = bnb[c] - mean * scv;
  }
  const int rr = t >> 3, c8 = (t & 7) * 8;
  #pragma unroll
  for (int pass = 0; pass < 2; pass++){
    int l = rr + pass * 32;
    bf16x8 v = *(const bf16x8*)(y + ((size_t)b * 4096 + lt*64 + l) * 512 + ct*64 + c8);
    #pragma unroll
    for (int s = 0; s < 8; s++) tile[l][c8+s] = bf2f((unsigned short)v[s]);
  }
  __syncthreads();
  #pragma unroll
  for (int pass = 0; pass < 2; pass++){
    int c = rr + pass * 32;
    float scv = scale_s[c], sh = shift_s[c];
    f32x4 o0, o1;
    #pragma unroll
    for (int s = 0; s < 4; s++){
      float v = tile[c8+s][c] * scv + sh;     o0[s] = v > 0.f ? v : 0.f;
      float w = tile[c8+4+s][c] * scv + sh;   o1[s] = w > 0.f ? w : 0.f;
    }
    float* dp = out + ((size_t)b * 512 + ct*64 + c) * 4096 + lt*64 + c8;
    *(f32x4*)dp = o0;
    *(f32x4*)(dp + 4) = o1;
  }
}

// ---------------------------------------------------------------------------
extern "C" void kernel_launch(void* const* d_in, const int* in_sizes, int n_in,
                              void* d_out, int out_size, void* d_ws, size_t ws_size,
                              hipStream_t stream)
{
  const float* x    = (const float*)d_in[0];
  const float* pos  = (const float*)d_in[1];
  const float* Wq   = (const float*)d_in[2];
  const float* bq   = (const float*)d_in[3];
  const float* Wk   = (const float*)d_in[4];
  const float* bk   = (const float*)d_in[5];
  const float* Wv   = (const float*)d_in[6];
  const float* bv   = (const float*)d_in[7];
  const float* Wq1  = (const float*)d_in[8];
  const float* bq1  = (const float*)d_in[9];
  const float* Wk1  = (const float*)d_in[10];
  const float* bk1  = (const float*)d_in[11];
  const float* gam  = (const float*)d_in[12];
  const float* bnw  = (const float*)d_in[13];
  const float* bnb  = (const float*)d_in[14];
  float* out = (float*)d_out;
  char* ws = (char*)d_ws;

  const size_t MB = 1ull << 20;
  const size_t OFF_XSB  = 0;                  // 32MB xs_bf, later y in-place
  const size_t OFF_QB   = 32*MB;              // 32MB Q
  const size_t OFF_Q1T  = 64*MB;              // 32MB Q1^T [8][512][4096]
  const size_t OFF_K1T  = 96*MB;              // 32MB K1^T
  const size_t OFF_SF   = 128*MB;             // 8MB  S fp32 [8][512][512]
  const size_t OFF_MIDB = 136*MB;             // 4MB
  const size_t OFF_MIDT = 140*MB;             // 4MB
  const size_t OFF_R0   = 144*MB;             // 32MB
  const size_t OFF_WBF  = 176*MB;             // 2.5MB
  const size_t OFF_B5   = 179*MB;             // 10KB
  const size_t OFF_DIAG = 180*MB;
  const size_t OFF_KSUM = OFF_DIAG + 16384;
  const size_t OFF_BNS  = OFF_KSUM + 16384;
  const size_t OFF_BNQ  = OFF_BNS + 2048;
  const size_t WS_NEED  = OFF_BNQ + 2048;
  if (ws_size < WS_NEED) return;

  unsigned short* xsb  = (unsigned short*)(ws + OFF_XSB);
  unsigned short* Qb   = (unsigned short*)(ws + OFF_QB);
  unsigned short* Q1T  = (unsigned short*)(ws + OFF_Q1T);
  unsigned short* K1T  = (unsigned short*)(ws + OFF_K1T);
  float*          Sf   = (float*)(ws + OFF_SF);
  unsigned short* midb = (unsigned short*)(ws + OFF_MIDB);
  unsigned short* midT = (unsigned short*)(ws + OFF_MIDT);
  unsigned short* r0   = (unsigned short*)(ws + OFF_R0);
  unsigned short* wbf  = (unsigned short*)(ws + OFF_WBF);
  float* bias5 = (float*)(ws + OFF_B5);
  float* diag = (float*)(ws + OFF_DIAG);
  float* ksum = (float*)(ws + OFF_KSUM);
  float* bnS  = (float*)(ws + OFF_BNS);
  float* bnQ  = (float*)(ws + OFF_BNQ);

  unsigned short* Kb = (unsigned short*)d_out;        // K,V live in d_out
  unsigned short* Vb = Kb + 16777216;

  hipMemsetAsync(ws + OFF_DIAG, 0, 16384 + 16384 + 2048 + 2048, stream);

  k_prep_w  <<<dim3(1024, 5), 256, 0, stream>>>(Wq, Wk, Wv, Wq1, Wk1, wbf);
  k_prep_b  <<<dim3(10),      256, 0, stream>>>(bq, bk, bv, bq1, bk1, bias5);
  k_build_xs<<<dim3(64, 8, 8),256, 0, stream>>>(x, pos, xsb);

  // fused 5-projection GEMM (writes Q, K, V, Q1^T, K1^T) — 8-phase 256² tiles
  gemm8_proj<<<dim3(1280), 512, 0, stream>>>(xsb, wbf, bias5, Qb, Kb, Vb, Q1T, K1T);

  k_reduce_kv<<<dim3(8, 8, 8), 256, 0, stream>>>(Kb, Vb, diag, ksum);
  k_z_r0<<<dim3(8192), 256, 0, stream>>>(Qb, ksum, diag, r0);

  // mid logits: S[b][i][j] = sum_l Q1[b,l,i] K1[b,l,j]  (A=Q1T, Bt=K1T, K=4096)
  gemm_mid<<<dim3(128), 256, 0, stream>>>(Q1T, K1T, Sf, 4096);

  k_softmax<<<dim3(4096), 64, 0, stream>>>(Sf, midb);
  k_transpose_bf<<<dim3(8, 8, 8), 256, 0, stream>>>(midb, midT, 512, 512);

  // result GEMM + residual + BN-stat epilogue (y in-place over xs_bf) — 8-phase
  gemm8_res<<<dim3(256), 512, 0, stream>>>(r0, midT, xsb, gam, bnS, bnQ);

  k_bn_finalize<<<dim3(64, 8, 8), 256, 0, stream>>>(xsb, bnS, bnQ, bnw, bnb, out);
}

// Round 4
// 261.259 us; speedup vs baseline: 1.1474x; 1.1474x over previous
//
#include <hip/hip_runtime.h>
#include <stdint.h>

typedef float f32x4 __attribute__((ext_vector_type(4)));
typedef short bf16x8 __attribute__((ext_vector_type(8)));
typedef short bf16x4 __attribute__((ext_vector_type(4)));

__device__ __forceinline__ float bf2f(unsigned short h){
  union { unsigned int u; float f; } v; v.u = ((unsigned int)h) << 16; return v.f;
}
__device__ __forceinline__ unsigned short f2bf(float f){
  union { float f; unsigned int u; } v; v.f = f;
  return (unsigned short)((v.u + 0x7fffu + ((v.u >> 16) & 1u)) >> 16);
}

typedef __attribute__((address_space(1))) const unsigned int ga_u32;
typedef __attribute__((address_space(3))) unsigned int ls_u32;
__device__ __forceinline__ void async_load16(const void* g, void* l){
  __builtin_amdgcn_global_load_lds((ga_u32*)g, (ls_u32*)l, 16, 0, 0);
}

#define CFENCE() asm volatile("" ::: "memory")
#define SB0() __builtin_amdgcn_sched_barrier(0)

// ---------------------------------------------------------------------------
// prep: fp32 weights -> bf16 (5 x 512x512), biases -> packed fp32 [5][512]
__global__ __launch_bounds__(256) void k_prep_w(
    const float* __restrict__ w0, const float* __restrict__ w1,
    const float* __restrict__ w2, const float* __restrict__ w3,
    const float* __restrict__ w4, unsigned short* __restrict__ out)
{
  int i = blockIdx.x * 256 + threadIdx.x;
  const float* w = (blockIdx.y == 0) ? w0 : (blockIdx.y == 1) ? w1 :
                   (blockIdx.y == 2) ? w2 : (blockIdx.y == 3) ? w3 : w4;
  out[(size_t)blockIdx.y * 262144 + i] = f2bf(w[i]);
}
__global__ __launch_bounds__(256) void k_prep_b(
    const float* __restrict__ b0, const float* __restrict__ b1,
    const float* __restrict__ b2, const float* __restrict__ b3,
    const float* __restrict__ b4, float* __restrict__ out)
{
  int i = blockIdx.x * 256 + threadIdx.x;   // 0..2559
  int s = i >> 9, r = i & 511;
  const float* b = (s == 0) ? b0 : (s == 1) ? b1 : (s == 2) ? b2 : (s == 3) ? b3 : b4;
  out[i] = b[r];
}

// ---------------------------------------------------------------------------
// build xs_bf[b][l][c] = bf16( x[b][c][l] + pos[l][c] )
__global__ __launch_bounds__(256) void k_build_xs(
    const float* __restrict__ x, const float* __restrict__ pos,
    unsigned short* __restrict__ xsb)
{
  __shared__ float tile[64][65];
  const int lt = blockIdx.x, ct = blockIdx.y, b = blockIdx.z;
  const int t = threadIdx.x;
  const int rr = t >> 3, c8 = (t & 7) * 8;
  #pragma unroll
  for (int pass = 0; pass < 2; pass++){
    int r = rr + pass * 32;
    const float* src = x + ((size_t)b * 512 + ct*64 + r) * 4096 + lt*64 + c8;
    f32x4 v0 = *(const f32x4*)src;
    f32x4 v1 = *(const f32x4*)(src + 4);
    #pragma unroll
    for (int s = 0; s < 4; s++){ tile[r][c8+s] = v0[s]; tile[r][c8+4+s] = v1[s]; }
  }
  __syncthreads();
  #pragma unroll
  for (int pass = 0; pass < 2; pass++){
    int ll = rr + pass * 32;
    int gl = lt*64 + ll;
    const float* pp = pos + (size_t)gl * 512 + ct*64 + c8;
    bf16x8 hv;
    #pragma unroll
    for (int s = 0; s < 8; s++)
      hv[s] = (short)f2bf(tile[c8+s][ll] + pp[s]);
    *(bf16x8*)(xsb + ((size_t)b * 4096 + gl) * 512 + ct*64 + c8) = hv;
  }
}

// ---------------------------------------------------------------------------
// generic bf16 transpose: in[z][R][C] -> out[z][C][R]   (used for mid only)
__global__ __launch_bounds__(256) void k_transpose_bf(
    const unsigned short* __restrict__ in, unsigned short* __restrict__ out,
    int R, int C)
{
  __shared__ float tile[64][65];
  const int rt = blockIdx.x, ct = blockIdx.y, z = blockIdx.z;
  const unsigned short* src = in  + (size_t)z * R * C;
  unsigned short*       dst = out + (size_t)z * R * C;
  const int t = threadIdx.x;
  const int rr = t >> 3, c8 = (t & 7) * 8;
  #pragma unroll
  for (int pass = 0; pass < 2; pass++){
    int r = rr + pass * 32;
    bf16x8 v = *(const bf16x8*)(src + (size_t)(rt*64 + r) * C + ct*64 + c8);
    #pragma unroll
    for (int s = 0; s < 8; s++) tile[r][c8+s] = bf2f((unsigned short)v[s]);
  }
  __syncthreads();
  #pragma unroll
  for (int pass = 0; pass < 2; pass++){
    int c = rr + pass * 32;
    bf16x8 hv;
    #pragma unroll
    for (int s = 0; s < 8; s++) hv[s] = (short)f2bf(tile[c8+s][c]);
    *(bf16x8*)(dst + (size_t)(ct*64 + c) * R + rt*64 + c8) = hv;
  }
}

// ---------------------------------------------------------------------------
// diagKV[b][c] = sum_l K*V ; Ksum[b][c] = sum_l K  (vectorized bf16x8 loads)
// grid (8 b, 64 lchunks of 64 rows), 256 threads: c8 = (t&63)*8, wave = lo.
__global__ __launch_bounds__(256) void k_reduce_kv(
    const unsigned short* __restrict__ Kb, const unsigned short* __restrict__ Vb,
    float* __restrict__ diag, float* __restrict__ ksum)
{
  const int b = blockIdx.x, lz = blockIdx.y * 64;
  const int t = threadIdx.x;
  const int c8 = (t & 63) * 8, lo = t >> 6;
  float d[8] = {0.f,0.f,0.f,0.f,0.f,0.f,0.f,0.f};
  float s[8] = {0.f,0.f,0.f,0.f,0.f,0.f,0.f,0.f};
  for (int l = lo; l < 64; l += 4){
    size_t base = ((size_t)b * 4096 + lz + l) * 512 + c8;
    bf16x8 kv = *(const bf16x8*)(Kb + base);
    bf16x8 vv = *(const bf16x8*)(Vb + base);
    #pragma unroll
    for (int j = 0; j < 8; j++){
      float kf = bf2f((unsigned short)kv[j]);
      float vf = bf2f((unsigned short)vv[j]);
      d[j] += kf * vf; s[j] += kf;
    }
  }
  __shared__ float red[2][4][512];
  f32x4 a0 = {d[0],d[1],d[2],d[3]}, a1 = {d[4],d[5],d[6],d[7]};
  f32x4 b0 = {s[0],s[1],s[2],s[3]}, b1 = {s[4],s[5],s[6],s[7]};
  *(f32x4*)&red[0][lo][c8]   = a0;  *(f32x4*)&red[0][lo][c8+4] = a1;
  *(f32x4*)&red[1][lo][c8]   = b0;  *(f32x4*)&red[1][lo][c8+4] = b1;
  __syncthreads();
  for (int cc = t; cc < 512; cc += 256){
    float dd = red[0][0][cc] + red[0][1][cc] + red[0][2][cc] + red[0][3][cc];
    float ss = red[1][0][cc] + red[1][1][cc] + red[1][2][cc] + red[1][3][cc];
    atomicAdd(&diag[b*512 + cc], dd);
    atomicAdd(&ksum[b*512 + cc], ss);
  }
}

// ---------------------------------------------------------------------------
// per row: Z = 1/sum_c Q*(Ksum+eps); r0 = Q*diagKV*Z  (bf16 out)
__global__ __launch_bounds__(256) void k_z_r0(
    const unsigned short* __restrict__ Qb, const float* __restrict__ ksum,
    const float* __restrict__ diag, unsigned short* __restrict__ r0)
{
  const int row = blockIdx.x * 4 + (threadIdx.x >> 6);
  const int lane = threadIdx.x & 63;
  const int b = row >> 12;
  bf16x8 q = *(const bf16x8*)(Qb + (size_t)row * 512 + lane * 8);
  float qf[8];
  #pragma unroll
  for (int s = 0; s < 8; s++) qf[s] = bf2f((unsigned short)q[s]);
  f32x4 k0 = *(const f32x4*)(ksum + b*512 + lane*8);
  f32x4 k1 = *(const f32x4*)(ksum + b*512 + lane*8 + 4);
  f32x4 d0 = *(const f32x4*)(diag + b*512 + lane*8);
  f32x4 d1 = *(const f32x4*)(diag + b*512 + lane*8 + 4);
  float den = 0.f;
  #pragma unroll
  for (int s = 0; s < 4; s++) den += qf[s]   * (k0[s] + 1e-6f);
  #pragma unroll
  for (int s = 0; s < 4; s++) den += qf[4+s] * (k1[s] + 1e-6f);
  #pragma unroll
  for (int m = 1; m < 64; m <<= 1) den += __shfl_xor(den, m);
  float Z = 1.0f / den;
  bf16x8 hv;
  #pragma unroll
  for (int s = 0; s < 4; s++) hv[s]   = (short)f2bf(qf[s]   * d0[s] * Z);
  #pragma unroll
  for (int s = 0; s < 4; s++) hv[4+s] = (short)f2bf(qf[4+s] * d1[s] * Z);
  *(bf16x8*)(r0 + (size_t)row * 512 + lane * 8) = hv;
}

// ---------------------------------------------------------------------------
// row softmax: S[row][0..511] fp32 -> mid bf16
__global__ __launch_bounds__(64) void k_softmax(
    const float* __restrict__ S, unsigned short* __restrict__ mid)
{
  const size_t row = blockIdx.x;
  const int lane = threadIdx.x;
  const float* p = S + row * 512 + lane * 8;
  f32x4 v0 = *(const f32x4*)p, v1 = *(const f32x4*)(p + 4);
  float mx = v0[0];
  #pragma unroll
  for (int s = 1; s < 4; s++) mx = fmaxf(mx, v0[s]);
  #pragma unroll
  for (int s = 0; s < 4; s++) mx = fmaxf(mx, v1[s]);
  #pragma unroll
  for (int m = 1; m < 64; m <<= 1) mx = fmaxf(mx, __shfl_xor(mx, m));
  float e[8]; float sum = 0.f;
  #pragma unroll
  for (int s = 0; s < 4; s++){ e[s]   = __expf(v0[s] - mx); sum += e[s]; }
  #pragma unroll
  for (int s = 0; s < 4; s++){ e[4+s] = __expf(v1[s] - mx); sum += e[4+s]; }
  #pragma unroll
  for (int m = 1; m < 64; m <<= 1) sum += __shfl_xor(sum, m);
  float inv = 1.0f / sum;
  bf16x8 hv;
  #pragma unroll
  for (int s = 0; s < 8; s++) hv[s] = (short)f2bf(e[s] * inv);
  *(bf16x8*)(mid + row * 512 + lane * 8) = hv;
}

// ===========================================================================
// 128x128 2-phase GEMM (mid-logits GEMM only; 128 blocks)
// ===========================================================================
#define GEMM_PRE()                                                            \
  const int tid = threadIdx.x;                                                \
  const int lane = tid & 63;                                                  \
  const int wave = tid >> 6;                                                  \
  const int wm = wave >> 1, wn = wave & 1;                                    \
  size_t aoff[4], boff[4]; int ldsq[4];                                       \
  _Pragma("unroll")                                                           \
  for (int i = 0; i < 4; i++){                                                \
    int qq = i*4 + wave;                                                      \
    int ch = qq*64 + lane;                                                    \
    int m  = ch >> 3, p = ch & 7;                                             \
    int lc = p ^ (m & 7);                                                     \
    aoff[i] = (size_t)(m0 + m) * K + lc*8;                                    \
    boff[i] = (size_t)(n0 + m) * K + lc*8;                                    \
    ldsq[i] = qq * 1024;                                                      \
  }                                                                           \
  f32x4 acc[4][4];                                                            \
  const f32x4 vzero = {0.f,0.f,0.f,0.f};                                      \
  _Pragma("unroll")                                                           \
  for (int i = 0; i < 4; i++)                                                 \
    _Pragma("unroll")                                                         \
    for (int j = 0; j < 4; j++) acc[i][j] = vzero;                            \
  int arow[4], brow[4];                                                       \
  _Pragma("unroll")                                                           \
  for (int f = 0; f < 4; f++){                                                \
    arow[f] = (wm*64 + f*16 + (lane & 15)) * 64;                              \
    brow[f] = (wn*64 + f*16 + (lane & 15)) * 64;                              \
  }                                                                           \
  const int kg = lane >> 4;                                                   \
  const int l7 = lane & 7;

#define GEMM_STAGE(buf, kt)                                                   \
  _Pragma("unroll")                                                           \
  for (int i = 0; i < 4; i++){                                                \
    async_load16(Ae + aoff[i] + (kt)*64, (char*)&smem[(buf)*8192] + ldsq[i]); \
    async_load16(Be + boff[i] + (kt)*64, (char*)&smem[16384 + (buf)*8192] + ldsq[i]); \
  }

#define GEMM_COMPUTE(buf)                                                     \
  _Pragma("unroll")                                                           \
  for (int ks = 0; ks < 2; ks++){                                             \
    bf16x8 a[4], b[4];                                                        \
    const int pa = (ks*4 + kg) ^ l7;                                          \
    _Pragma("unroll")                                                         \
    for (int f = 0; f < 4; f++){                                              \
      a[f] = *(const bf16x8*)&smem[(buf)*8192 + arow[f] + pa*8];              \
      b[f] = *(const bf16x8*)&smem[16384 + (buf)*8192 + brow[f] + pa*8];      \
    }                                                                         \
    _Pragma("unroll")                                                         \
    for (int i = 0; i < 4; i++)                                               \
      _Pragma("unroll")                                                       \
      for (int j = 0; j < 4; j++)                                             \
        acc[i][j] = __builtin_amdgcn_mfma_f32_16x16x32_bf16(a[i], b[j], acc[i][j], 0, 0, 0); \
  }

#define GEMM_KLOOP(nkt)                                                       \
  GEMM_STAGE(0, 0);                                                           \
  __syncthreads();                                                            \
  int cur = 0;                                                                \
  for (int kt = 0; kt < (nkt); kt++){                                         \
    if (kt + 1 < (nkt)) { GEMM_STAGE(cur ^ 1, kt + 1); }                      \
    GEMM_COMPUTE(cur);                                                        \
    __syncthreads();                                                          \
    cur ^= 1;                                                                 \
  }

// mid logits: S[b][i][j] = sum_l Q1T[b,i,l] * K1T[b,j,l]  (K=4096)
__global__ __launch_bounds__(256) void gemm_mid(
    const unsigned short* __restrict__ A,
    const unsigned short* __restrict__ Bt,
    float* __restrict__ outf, int K)
{
  __shared__ unsigned short smem[32768];
  const int bid = blockIdx.x;
  const int cpx = gridDim.x >> 3;
  const int wgid = (bid & 7) * cpx + (bid >> 3);
  const int z = wgid >> 4;
  const int mtile = (wgid >> 2) & 3, ntile = wgid & 3;
  const int m0 = mtile * 128, n0 = ntile * 128;
  const unsigned short* Ae = A  + (size_t)z * 512 * (size_t)K;
  const unsigned short* Be = Bt + (size_t)z * 512 * (size_t)K;

  GEMM_PRE();
  GEMM_KLOOP(K >> 6);

  const int lr = lane >> 4;
  const int lc16 = lane & 15;
  #pragma unroll
  for (int j = 0; j < 4; j++){
    int cidx = n0 + wn*64 + j*16 + lc16;
    #pragma unroll
    for (int i = 0; i < 4; i++){
      int r = m0 + wm*64 + i*16 + lr*4;
      #pragma unroll
      for (int q = 0; q < 4; q++)
        outf[(size_t)z * 262144 + (size_t)(r + q) * 512 + cidx] = acc[i][j][q];
    }
  }
}

// ===========================================================================
// 256x256-tile, 8-wave, 8-phase counted-vmcnt GEMM (T2+T3+T4+T5).
// Phase ledger as R3 (verified correct); NEW: sched_barrier(0) pins around
// each MFMA cluster (rule #18: register-only MFMAs otherwise sink across
// raw s_barrier phases), and LDS-coalesced epilogues.
// ===========================================================================

#define G8_PRE(AE, BE, N0ABS)                                                 \
  const int t = threadIdx.x;                                                  \
  const int lane = t & 63;                                                    \
  const int wave = t >> 6;                                                    \
  const int wm = wave >> 2, wn = wave & 3;                                    \
  const int l15 = lane & 15, kg = lane >> 4;                                  \
  const int lcw = ((t & 7) ^ ((t >> 3) & 7)) * 8;                             \
  const unsigned short* a_src = (AE) + (size_t)(m0 + (t >> 3)) * 512 + lcw;   \
  const unsigned short* b_src = (BE) + (size_t)((N0ABS) + (t >> 3)) * 512 + lcw; \
  f32x4 acc[8][4];                                                            \
  const f32x4 vzero = {0.f,0.f,0.f,0.f};                                      \
  _Pragma("unroll")                                                           \
  for (int i = 0; i < 8; i++)                                                 \
    _Pragma("unroll")                                                         \
    for (int j = 0; j < 4; j++) acc[i][j] = vzero;                            \
  bf16x8 af[4][2], bf[4][2];

#define STAGE_A(D,H,TT) do{                                                   \
  async_load16(a_src + (H)*65536 + (TT)*64,                                   \
               (char*)smem + ((D)*16384 + (H)*8192 + t*8)*2);                 \
  async_load16(a_src + (H)*65536 + 32768 + (TT)*64,                           \
               (char*)smem + ((D)*16384 + (H)*8192 + 4096 + t*8)*2);          \
}while(0)

#define STAGE_B(D,H,TT) do{                                                   \
  async_load16(b_src + (H)*65536 + (TT)*64,                                   \
               (char*)smem + (32768 + (D)*16384 + (H)*8192 + t*8)*2);         \
  async_load16(b_src + (H)*65536 + 32768 + (TT)*64,                           \
               (char*)smem + (32768 + (D)*16384 + (H)*8192 + 4096 + t*8)*2);  \
}while(0)

#define READ_A(D, MH) do{                                                     \
  _Pragma("unroll")                                                           \
  for (int mfl = 0; mfl < 4; ++mfl){                                          \
    const int rl = ((MH)*4 + mfl)*16 + l15;                                   \
    _Pragma("unroll")                                                         \
    for (int ks = 0; ks < 2; ++ks){                                           \
      const int ck = (ks*4 + kg) ^ (rl & 7);                                  \
      af[mfl][ks] = *(const bf16x8*)&smem[(D)*16384 + wm*8192 + rl*64 + ck*8];\
    }                                                                         \
  }                                                                           \
}while(0)

#define READ_B(D, NP) do{                                                     \
  _Pragma("unroll")                                                           \
  for (int nfl = 0; nfl < 2; ++nfl){                                          \
    const int nf = (NP)*2 + nfl;                                              \
    const int rbl = (wn & 1)*64 + nf*16 + l15;                                \
    _Pragma("unroll")                                                         \
    for (int ks = 0; ks < 2; ++ks){                                           \
      const int ck = (ks*4 + kg) ^ (rbl & 7);                                 \
      bf[nf][ks] = *(const bf16x8*)&smem[32768 + (D)*16384 + (wn>>1)*8192 + rbl*64 + ck*8]; \
    }                                                                         \
  }                                                                           \
}while(0)

#define QUAD(MH, NP)                                                          \
  _Pragma("unroll")                                                           \
  for (int mfl = 0; mfl < 4; ++mfl)                                           \
    _Pragma("unroll")                                                         \
    for (int nfl = 0; nfl < 2; ++nfl)                                         \
      _Pragma("unroll")                                                       \
      for (int ks = 0; ks < 2; ++ks)                                          \
        acc[(MH)*4+mfl][(NP)*2+nfl] = __builtin_amdgcn_mfma_f32_16x16x32_bf16(\
            af[mfl][ks], bf[(NP)*2+nfl][ks], acc[(MH)*4+mfl][(NP)*2+nfl], 0,0,0);

#define PH_MID()  CFENCE(); __builtin_amdgcn_s_barrier();                     \
  __builtin_amdgcn_s_setprio(1); SB0()
#define PH_END()  SB0(); __builtin_amdgcn_s_setprio(0); CFENCE();             \
  __builtin_amdgcn_s_barrier(); CFENCE()
#define PH_END_VM4() SB0(); __builtin_amdgcn_s_setprio(0);                    \
  asm volatile("s_waitcnt vmcnt(4)" ::: "memory");                            \
  __builtin_amdgcn_s_barrier(); CFENCE()
#define PH_END_VM0() SB0(); __builtin_amdgcn_s_setprio(0);                    \
  asm volatile("s_waitcnt vmcnt(0)" ::: "memory");                            \
  __builtin_amdgcn_s_barrier(); CFENCE()

// K = 512 fixed -> nkt = 8, niter = 4
#define G8_KLOOP()                                                            \
  STAGE_A(0,0,0); STAGE_A(0,1,0); STAGE_B(0,0,0); STAGE_B(0,1,0);             \
  STAGE_B(1,0,1); STAGE_B(1,1,1);                                             \
  asm volatile("s_waitcnt vmcnt(4)" ::: "memory");                            \
  __builtin_amdgcn_s_barrier(); CFENCE();                                     \
  for (int it = 0; it < 3; ++it){                                             \
    const int t1 = 2*it + 1, t2 = 2*it + 2, t3 = 2*it + 3;                    \
    READ_A(0,0); READ_B(0,0); STAGE_A(1,0,t1);                                \
    PH_MID(); QUAD(0,0); PH_END();                                            \
    READ_B(0,1); STAGE_A(1,1,t1);                                             \
    PH_MID(); QUAD(0,1); PH_END();                                            \
    READ_A(0,1); STAGE_B(0,0,t2);                                             \
    PH_MID(); QUAD(1,0); PH_END();                                            \
    STAGE_A(0,0,t2);                                                          \
    PH_MID(); QUAD(1,1); PH_END_VM4();                                        \
    READ_A(1,0); READ_B(1,0); STAGE_A(0,1,t2);                                \
    PH_MID(); QUAD(0,0); PH_END();                                            \
    READ_B(1,1); STAGE_B(0,1,t2);                                             \
    PH_MID(); QUAD(0,1); PH_END();                                            \
    READ_A(1,1); STAGE_B(1,0,t3);                                             \
    PH_MID(); QUAD(1,0); PH_END();                                            \
    STAGE_B(1,1,t3);                                                          \
    PH_MID(); QUAD(1,1); PH_END_VM4();                                        \
  }                                                                           \
  { /* last iteration: tiles 6 (dbuf0), 7 (dbuf1) */                          \
    READ_A(0,0); READ_B(0,0); STAGE_A(1,0,7);                                 \
    PH_MID(); QUAD(0,0); PH_END();                                            \
    READ_B(0,1); STAGE_A(1,1,7);                                              \
    PH_MID(); QUAD(0,1); PH_END();                                            \
    READ_A(0,1);                                                              \
    PH_MID(); QUAD(1,0); PH_END();                                            \
    PH_MID(); QUAD(1,1); PH_END_VM0();                                        \
    READ_A(1,0); READ_B(1,0);                                                 \
    PH_MID(); QUAD(0,0); PH_END();                                            \
    READ_B(1,1);                                                              \
    PH_MID(); QUAD(0,1); PH_END();                                            \
    READ_A(1,1);                                                              \
    PH_MID(); QUAD(1,0); PH_END();                                            \
    PH_MID(); QUAD(1,1); PH_END();                                            \
  }

// ---------------------------------------------------------------------------
// fused 5-projection 8-phase GEMM. grid = 1280 x 512 threads.
__global__ __launch_bounds__(512, 2) void gemm8_proj(
    const unsigned short* __restrict__ A,
    const unsigned short* __restrict__ W,
    const float* __restrict__ bias5,
    unsigned short* __restrict__ Qb, unsigned short* __restrict__ Kb,
    unsigned short* __restrict__ Vb, unsigned short* __restrict__ Q1T,
    unsigned short* __restrict__ K1T)
{
  __shared__ unsigned short smem[65536];   // 128KB
  const int bid = blockIdx.x;
  const int wgid = (bid & 7) * 160 + (bid >> 3);   // 1280 % 8 == 0: bijective
  const int mtile = wgid / 10;
  const int nslot = wgid % 10;
  const int slot = nslot >> 1;
  const int ncol = nslot & 1;
  const int m0 = mtile * 256;
  const int nc0 = ncol * 256;

  G8_PRE(A, W + (size_t)slot * 262144, nc0);
  G8_KLOOP();

  if (slot < 3){
    // LDS-coalesced epilogue: acc -> LDS (XOR bits 4-5 by rl>>2) -> 16B stores
    unsigned short* o = (slot == 0) ? Qb : (slot == 1) ? Kb : Vb;
    const bool relu = (slot < 2);
    __syncthreads();
    #pragma unroll
    for (int nf = 0; nf < 4; nf++){
      int cl = wn*64 + nf*16 + l15;
      float bb = bias5[slot*512 + nc0 + cl];
      #pragma unroll
      for (int mf = 0; mf < 8; mf++){
        int rbase = wm*128 + mf*16 + kg*4;
        #pragma unroll
        for (int q = 0; q < 4; q++){
          float v = acc[mf][nf][q] + bb;
          if (relu) v = v > 0.f ? v : 0.f;
          int rl = rbase + q;
          smem[rl*256 + (cl ^ (((rl >> 2) & 3) << 4))] = f2bf(v);
        }
      }
    }
    __syncthreads();
    const int c0 = (t & 31) * 8;
    #pragma unroll
    for (int rep = 0; rep < 16; rep++){
      int rl = rep*16 + (t >> 5);
      bf16x8 v = *(const bf16x8*)&smem[rl*256 + (c0 ^ (((rl >> 2) & 3) << 4))];
      *(bf16x8*)(o + (size_t)(m0 + rl) * 512 + nc0 + c0) = v;
    }
  } else {
    // transposed output via in-LDS 256x256 transpose (chunk-XOR swizzled)
    unsigned short* o = (slot == 3) ? Q1T : K1T;
    const int b = mtile >> 4;
    const int l0 = (mtile & 15) * 256;
    __syncthreads();
    #pragma unroll
    for (int nf = 0; nf < 4; nf++){
      int cl_ = wn*64 + nf*16 + l15;
      float bb = bias5[slot*512 + nc0 + cl_];
      #pragma unroll
      for (int mf = 0; mf < 8; mf++){
        #pragma unroll
        for (int q = 0; q < 4; q++){
          int ll = wm*128 + mf*16 + kg*4 + q;
          int sw = ((ll >> 3) ^ (cl_ & 7)) * 8 + (ll & 7);
          smem[cl_*256 + sw] = f2bf(acc[mf][nf][q] + bb);
        }
      }
    }
    __syncthreads();
    #pragma unroll
    for (int rep = 0; rep < 16; rep++){
      int c = rep*16 + (t >> 5);
      int lch = t & 31;
      bf16x8 v = *(const bf16x8*)&smem[c*256 + (lch ^ (c & 7))*8];
      *(bf16x8*)(o + ((size_t)b*512 + nc0 + c)*4096 + l0 + lch*8) = v;
    }
  }
}

// ---------------------------------------------------------------------------
// result 8-phase GEMM: y = xs + gamma*(r0 @ midT^T) in-place + BN stats.
// grid = 256 x 512 threads. LDS-coalesced RMW epilogue.
__global__ __launch_bounds__(512, 2) void gemm8_res(
    const unsigned short* __restrict__ A,        // r0 [32768][512]
    const unsigned short* __restrict__ Bt,       // midT [8][512][512]
    unsigned short* __restrict__ outh,           // xs bf16, in-place -> y
    const float* __restrict__ gamma_p,
    float* __restrict__ bnS, float* __restrict__ bnQ)
{
  __shared__ unsigned short smem[65536];
  const int bid = blockIdx.x;
  const int wgid = (bid & 7) * 32 + (bid >> 3);   // 256 % 8 == 0
  const int mtile = wgid >> 1;
  const int ntile = wgid & 1;
  const int m0 = mtile * 256;
  const int nc0 = ntile * 256;

  G8_PRE(A, Bt + (size_t)(mtile >> 4) * 262144, nc0);
  G8_KLOOP();

  const float g = gamma_p[0];
  __syncthreads();
  // stage 1: g*acc -> LDS bf16 swizzled
  #pragma unroll
  for (int nf = 0; nf < 4; nf++){
    int cl = wn*64 + nf*16 + l15;
    #pragma unroll
    for (int mf = 0; mf < 8; mf++){
      int rbase = wm*128 + mf*16 + kg*4;
      #pragma unroll
      for (int q = 0; q < 4; q++){
        int rl = rbase + q;
        smem[rl*256 + (cl ^ (((rl >> 2) & 3) << 4))] = f2bf(g * acc[mf][nf][q]);
      }
    }
  }
  __syncthreads();
  // stage 2: coalesced RMW + per-thread col partials (8 fixed cols)
  float sc[8] = {0.f,0.f,0.f,0.f,0.f,0.f,0.f,0.f};
  float sq[8] = {0.f,0.f,0.f,0.f,0.f,0.f,0.f,0.f};
  const int c0 = (t & 31) * 8;
  #pragma unroll
  for (int rep = 0; rep < 16; rep++){
    int rl = rep*16 + (t >> 5);
    bf16x8 ga = *(const bf16x8*)&smem[rl*256 + (c0 ^ (((rl >> 2) & 3) << 4))];
    size_t gidx = (size_t)(m0 + rl) * 512 + nc0 + c0;
    bf16x8 xv = *(const bf16x8*)(outh + gidx);
    bf16x8 yv;
    #pragma unroll
    for (int j = 0; j < 8; j++){
      float y = bf2f((unsigned short)xv[j]) + bf2f((unsigned short)ga[j]);
      yv[j] = (short)f2bf(y);
      sc[j] += y; sq[j] += y * y;
    }
    *(bf16x8*)(outh + gidx) = yv;
  }
  __syncthreads();
  // stage 3: reduce col partials across 16 row-groups, then atomics
  float* red = (float*)(void*)smem;   // [16][256] sc ; +4096: [16][256] sq
  const int tg = t >> 5;
  f32x4 s0 = {sc[0],sc[1],sc[2],sc[3]}, s1 = {sc[4],sc[5],sc[6],sc[7]};
  f32x4 q0 = {sq[0],sq[1],sq[2],sq[3]}, q1 = {sq[4],sq[5],sq[6],sq[7]};
  *(f32x4*)&red[tg*256 + c0]          = s0;  *(f32x4*)&red[tg*256 + c0 + 4]          = s1;
  *(f32x4*)&red[4096 + tg*256 + c0]   = q0;  *(f32x4*)&red[4096 + tg*256 + c0 + 4]   = q1;
  __syncthreads();
  if (t < 256){
    float ss = 0.f, qq = 0.f;
    #pragma unroll
    for (int gg = 0; gg < 16; gg++){
      ss += red[gg*256 + t];
      qq += red[4096 + gg*256 + t];
    }
    atomicAdd(&bnS[nc0 + t], ss);
    atomicAdd(&bnQ[nc0 + t], qq);
  }
}

// ---------------------------------------------------------------------------
// finalize: y[b][l][c] bf16 -> out[b][c][l] fp32, BN affine + relu
__global__ __launch_bounds__(256) void k_bn_finalize(
    const unsigned short* __restrict__ y, const float* __restrict__ bnS,
    const float* __restrict__ bnQ, const float* __restrict__ bnw,
    const float* __restrict__ bnb, float* __restrict__ out)
{
  __shared__ float tile[64][65];
  __shared__ float scale_s[64], shift_s[64];
  const int lt = blockIdx.x, ct = blockIdx.y, b = blockIdx.z;
  const int t = threadIdx.x;
  if (t < 64){
    int c = ct*64 + t;
    float s = bnS[c], q = bnQ[c];
    float mean = s * (1.0f / 32768.0f);
    float var  = q * (1.0f / 32768.0f) - mean * mean;
    float inv  = rsqrtf(var + 1e-5f);
    float scv  = bnw[c] * inv;
    scale_s[t] = scv;
    shift_s[t] = bnb[c] - mean * scv;
  }
  const int rr = t >> 3, c8 = (t & 7) * 8;
  #pragma unroll
  for (int pass = 0; pass < 2; pass++){
    int l = rr + pass * 32;
    bf16x8 v = *(const bf16x8*)(y + ((size_t)b * 4096 + lt*64 + l) * 512 + ct*64 + c8);
    #pragma unroll
    for (int s = 0; s < 8; s++) tile[l][c8+s] = bf2f((unsigned short)v[s]);
  }
  __syncthreads();
  #pragma unroll
  for (int pass = 0; pass < 2; pass++){
    int c = rr + pass * 32;
    float scv = scale_s[c], sh = shift_s[c];
    f32x4 o0, o1;
    #pragma unroll
    for (int s = 0; s < 4; s++){
      float v = tile[c8+s][c] * scv + sh;     o0[s] = v > 0.f ? v : 0.f;
      float w = tile[c8+4+s][c] * scv + sh;   o1[s] = w > 0.f ? w : 0.f;
    }
    float* dp = out + ((size_t)b * 512 + ct*64 + c) * 4096 + lt*64 + c8;
    *(f32x4*)dp = o0;
    *(f32x4*)(dp + 4) = o1;
  }
}

// ---------------------------------------------------------------------------
extern "C" void kernel_launch(void* const* d_in, const int* in_sizes, int n_in,
                              void* d_out, int out_size, void* d_ws, size_t ws_size,
                              hipStream_t stream)
{
  const float* x    = (const float*)d_in[0];
  const float* pos  = (const float*)d_in[1];
  const float* Wq   = (const float*)d_in[2];
  const float* bq   = (const float*)d_in[3];
  const float* Wk   = (const float*)d_in[4];
  const float* bk   = (const float*)d_in[5];
  const float* Wv   = (const float*)d_in[6];
  const float* bv   = (const float*)d_in[7];
  const float* Wq1  = (const float*)d_in[8];
  const float* bq1  = (const float*)d_in[9];
  const float* Wk1  = (const float*)d_in[10];
  const float* bk1  = (const float*)d_in[11];
  const float* gam  = (const float*)d_in[12];
  const float* bnw  = (const float*)d_in[13];
  const float* bnb  = (const float*)d_in[14];
  float* out = (float*)d_out;
  char* ws = (char*)d_ws;

  const size_t MB = 1ull << 20;
  const size_t OFF_XSB  = 0;                  // 32MB xs_bf, later y in-place
  const size_t OFF_QB   = 32*MB;              // 32MB Q
  const size_t OFF_Q1T  = 64*MB;              // 32MB Q1^T [8][512][4096]
  const size_t OFF_K1T  = 96*MB;              // 32MB K1^T
  const size_t OFF_SF   = 128*MB;             // 8MB  S fp32 [8][512][512]
  const size_t OFF_MIDB = 136*MB;             // 4MB
  const size_t OFF_MIDT = 140*MB;             // 4MB
  const size_t OFF_R0   = 144*MB;             // 32MB
  const size_t OFF_WBF  = 176*MB;             // 2.5MB
  const size_t OFF_B5   = 179*MB;             // 10KB
  const size_t OFF_DIAG = 180*MB;
  const size_t OFF_KSUM = OFF_DIAG + 16384;
  const size_t OFF_BNS  = OFF_KSUM + 16384;
  const size_t OFF_BNQ  = OFF_BNS + 2048;
  const size_t WS_NEED  = OFF_BNQ + 2048;
  if (ws_size < WS_NEED) return;

  unsigned short* xsb  = (unsigned short*)(ws + OFF_XSB);
  unsigned short* Qb   = (unsigned short*)(ws + OFF_QB);
  unsigned short* Q1T  = (unsigned short*)(ws + OFF_Q1T);
  unsigned short* K1T  = (unsigned short*)(ws + OFF_K1T);
  float*          Sf   = (float*)(ws + OFF_SF);
  unsigned short* midb = (unsigned short*)(ws + OFF_MIDB);
  unsigned short* midT = (unsigned short*)(ws + OFF_MIDT);
  unsigned short* r0   = (unsigned short*)(ws + OFF_R0);
  unsigned short* wbf  = (unsigned short*)(ws + OFF_WBF);
  float* bias5 = (float*)(ws + OFF_B5);
  float* diag = (float*)(ws + OFF_DIAG);
  float* ksum = (float*)(ws + OFF_KSUM);
  float* bnS  = (float*)(ws + OFF_BNS);
  float* bnQ  = (float*)(ws + OFF_BNQ);

  unsigned short* Kb = (unsigned short*)d_out;        // K,V live in d_out
  unsigned short* Vb = Kb + 16777216;

  hipMemsetAsync(ws + OFF_DIAG, 0, 16384 + 16384 + 2048 + 2048, stream);

  k_prep_w  <<<dim3(1024, 5), 256, 0, stream>>>(Wq, Wk, Wv, Wq1, Wk1, wbf);
  k_prep_b  <<<dim3(10),      256, 0, stream>>>(bq, bk, bv, bq1, bk1, bias5);
  k_build_xs<<<dim3(64, 8, 8),256, 0, stream>>>(x, pos, xsb);

  // fused 5-projection GEMM (writes Q, K, V, Q1^T, K1^T) — 8-phase 256² tiles
  gemm8_proj<<<dim3(1280), 512, 0, stream>>>(xsb, wbf, bias5, Qb, Kb, Vb, Q1T, K1T);

  k_reduce_kv<<<dim3(8, 64), 256, 0, stream>>>(Kb, Vb, diag, ksum);
  k_z_r0<<<dim3(8192), 256, 0, stream>>>(Qb, ksum, diag, r0);

  // mid logits: S[b][i][j] = sum_l Q1[b,l,i] K1[b,l,j]  (A=Q1T, Bt=K1T, K=4096)
  gemm_mid<<<dim3(128), 256, 0, stream>>>(Q1T, K1T, Sf, 4096);

  k_softmax<<<dim3(4096), 64, 0, stream>>>(Sf, midb);
  k_transpose_bf<<<dim3(8, 8, 8), 256, 0, stream>>>(midb, midT, 512, 512);

  // result GEMM + residual + BN-stat epilogue (y in-place over xs_bf) — 8-phase
  gemm8_res<<<dim3(256), 512, 0, stream>>>(r0, midT, xsb, gam, bnS, bnQ);

  k_bn_finalize<<<dim3(64, 8, 8), 256, 0, stream>>>(xsb, bnS, bnQ, bnw, bnb, out);
}

// Round 5
// 234.804 us; speedup vs baseline: 1.2767x; 1.1127x over previous
//
#include <hip/hip_runtime.h>
#include <stdint.h>

typedef float f32x4 __attribute__((ext_vector_type(4)));
typedef short bf16x8 __attribute__((ext_vector_type(8)));

__device__ __forceinline__ float bf2f(unsigned short h){
  union { unsigned int u; float f; } v; v.u = ((unsigned int)h) << 16; return v.f;
}
__device__ __forceinline__ unsigned short f2bf(float f){
  union { float f; unsigned int u; } v; v.f = f;
  return (unsigned short)((v.u + 0x7fffu + ((v.u >> 16) & 1u)) >> 16);
}

typedef __attribute__((address_space(1))) const unsigned int ga_u32;
typedef __attribute__((address_space(3))) unsigned int ls_u32;
__device__ __forceinline__ void async_load16(const void* g, void* l){
  __builtin_amdgcn_global_load_lds((ga_u32*)g, (ls_u32*)l, 16, 0, 0);
}

#define CFENCE() asm volatile("" ::: "memory")
#define SB0() __builtin_amdgcn_sched_barrier(0)

// ---------------------------------------------------------------------------
// prep: fp32 weights -> bf16 (5 x 512x512), biases -> packed fp32 [5][512]
__global__ __launch_bounds__(256) void k_prep_w(
    const float* __restrict__ w0, const float* __restrict__ w1,
    const float* __restrict__ w2, const float* __restrict__ w3,
    const float* __restrict__ w4, unsigned short* __restrict__ out)
{
  int i = blockIdx.x * 256 + threadIdx.x;
  const float* w = (blockIdx.y == 0) ? w0 : (blockIdx.y == 1) ? w1 :
                   (blockIdx.y == 2) ? w2 : (blockIdx.y == 3) ? w3 : w4;
  out[(size_t)blockIdx.y * 262144 + i] = f2bf(w[i]);
}
__global__ __launch_bounds__(256) void k_prep_b(
    const float* __restrict__ b0, const float* __restrict__ b1,
    const float* __restrict__ b2, const float* __restrict__ b3,
    const float* __restrict__ b4, float* __restrict__ out)
{
  int i = blockIdx.x * 256 + threadIdx.x;   // 0..2559
  int s = i >> 9, r = i & 511;
  const float* b = (s == 0) ? b0 : (s == 1) ? b1 : (s == 2) ? b2 : (s == 3) ? b3 : b4;
  out[i] = b[r];
}

// ---------------------------------------------------------------------------
// build xs_bf[b][l][c] = bf16( x[b][c][l] + pos[l][c] )
__global__ __launch_bounds__(256) void k_build_xs(
    const float* __restrict__ x, const float* __restrict__ pos,
    unsigned short* __restrict__ xsb)
{
  __shared__ float tile[64][65];
  const int lt = blockIdx.x, ct = blockIdx.y, b = blockIdx.z;
  const int t = threadIdx.x;
  const int rr = t >> 3, c8 = (t & 7) * 8;
  #pragma unroll
  for (int pass = 0; pass < 2; pass++){
    int r = rr + pass * 32;
    const float* src = x + ((size_t)b * 512 + ct*64 + r) * 4096 + lt*64 + c8;
    f32x4 v0 = *(const f32x4*)src;
    f32x4 v1 = *(const f32x4*)(src + 4);
    #pragma unroll
    for (int s = 0; s < 4; s++){ tile[r][c8+s] = v0[s]; tile[r][c8+4+s] = v1[s]; }
  }
  __syncthreads();
  #pragma unroll
  for (int pass = 0; pass < 2; pass++){
    int ll = rr + pass * 32;
    int gl = lt*64 + ll;
    const float* pp = pos + (size_t)gl * 512 + ct*64 + c8;
    bf16x8 hv;
    #pragma unroll
    for (int s = 0; s < 8; s++)
      hv[s] = (short)f2bf(tile[c8+s][ll] + pp[s]);
    *(bf16x8*)(xsb + ((size_t)b * 4096 + gl) * 512 + ct*64 + c8) = hv;
  }
}

// ---------------------------------------------------------------------------
// mid transpose with diag fold: midT[z][d][c] = mid[z][c][d] * diag[z][c]
__global__ __launch_bounds__(256) void k_transpose_scale(
    const unsigned short* __restrict__ in, const float* __restrict__ diag,
    unsigned short* __restrict__ out)
{
  __shared__ float tile[64][65];
  const int rt = blockIdx.x, ct = blockIdx.y, z = blockIdx.z;
  const unsigned short* src = in  + (size_t)z * 262144;
  unsigned short*       dst = out + (size_t)z * 262144;
  const int t = threadIdx.x;
  const int rr = t >> 3, c8 = (t & 7) * 8;
  #pragma unroll
  for (int pass = 0; pass < 2; pass++){
    int r = rr + pass * 32;
    bf16x8 v = *(const bf16x8*)(src + (size_t)(rt*64 + r) * 512 + ct*64 + c8);
    #pragma unroll
    for (int s = 0; s < 8; s++) tile[r][c8+s] = bf2f((unsigned short)v[s]);
  }
  __syncthreads();
  f32x4 dg0 = *(const f32x4*)(diag + z*512 + rt*64 + c8);
  f32x4 dg1 = *(const f32x4*)(diag + z*512 + rt*64 + c8 + 4);
  #pragma unroll
  for (int pass = 0; pass < 2; pass++){
    int c = rr + pass * 32;
    bf16x8 hv;
    #pragma unroll
    for (int s = 0; s < 4; s++) hv[s]   = (short)f2bf(tile[c8+s][c]   * dg0[s]);
    #pragma unroll
    for (int s = 0; s < 4; s++) hv[4+s] = (short)f2bf(tile[c8+4+s][c] * dg1[s]);
    *(bf16x8*)(dst + (size_t)(ct*64 + c) * 512 + rt*64 + c8) = hv;
  }
}

// ---------------------------------------------------------------------------
// Z[row] = 1 / sum_c Q[row,c]*(Ksum[b,c]+eps)
__global__ __launch_bounds__(256) void k_z(
    const unsigned short* __restrict__ Qb, const float* __restrict__ ksum,
    float* __restrict__ Z)
{
  const int row = blockIdx.x * 4 + (threadIdx.x >> 6);
  const int lane = threadIdx.x & 63;
  const int b = row >> 12;
  bf16x8 q = *(const bf16x8*)(Qb + (size_t)row * 512 + lane * 8);
  f32x4 k0 = *(const f32x4*)(ksum + b*512 + lane*8);
  f32x4 k1 = *(const f32x4*)(ksum + b*512 + lane*8 + 4);
  float den = 0.f;
  #pragma unroll
  for (int s = 0; s < 4; s++) den += bf2f((unsigned short)q[s])   * (k0[s] + 1e-6f);
  #pragma unroll
  for (int s = 0; s < 4; s++) den += bf2f((unsigned short)q[4+s]) * (k1[s] + 1e-6f);
  #pragma unroll
  for (int m = 1; m < 64; m <<= 1) den += __shfl_xor(den, m);
  if (lane == 0) Z[row] = 1.0f / den;
}

// ---------------------------------------------------------------------------
// row softmax over S = S0 + S1 (split-K partials): -> mid bf16
__global__ __launch_bounds__(64) void k_softmax(
    const float* __restrict__ S0, const float* __restrict__ S1,
    unsigned short* __restrict__ mid)
{
  const size_t row = blockIdx.x;
  const int lane = threadIdx.x;
  const float* p0 = S0 + row * 512 + lane * 8;
  const float* p1 = S1 + row * 512 + lane * 8;
  f32x4 v0 = *(const f32x4*)p0 + *(const f32x4*)p1;
  f32x4 v1 = *(const f32x4*)(p0 + 4) + *(const f32x4*)(p1 + 4);
  float mx = v0[0];
  #pragma unroll
  for (int s = 1; s < 4; s++) mx = fmaxf(mx, v0[s]);
  #pragma unroll
  for (int s = 0; s < 4; s++) mx = fmaxf(mx, v1[s]);
  #pragma unroll
  for (int m = 1; m < 64; m <<= 1) mx = fmaxf(mx, __shfl_xor(mx, m));
  float e[8]; float sum = 0.f;
  #pragma unroll
  for (int s = 0; s < 4; s++){ e[s]   = __expf(v0[s] - mx); sum += e[s]; }
  #pragma unroll
  for (int s = 0; s < 4; s++){ e[4+s] = __expf(v1[s] - mx); sum += e[4+s]; }
  #pragma unroll
  for (int m = 1; m < 64; m <<= 1) sum += __shfl_xor(sum, m);
  float inv = 1.0f / sum;
  bf16x8 hv;
  #pragma unroll
  for (int s = 0; s < 8; s++) hv[s] = (short)f2bf(e[s] * inv);
  *(bf16x8*)(mid + row * 512 + lane * 8) = hv;
}

// ===========================================================================
// 128x128 2-phase GEMM machinery (mid-logits GEMM, split-K, 256 blocks)
// ===========================================================================
#define GEMM_PRE()                                                            \
  const int tid = threadIdx.x;                                                \
  const int lane = tid & 63;                                                  \
  const int wave = tid >> 6;                                                  \
  const int wm = wave >> 1, wn = wave & 1;                                    \
  size_t aoff[4], boff[4]; int ldsq[4];                                       \
  _Pragma("unroll")                                                           \
  for (int i = 0; i < 4; i++){                                                \
    int qq = i*4 + wave;                                                      \
    int ch = qq*64 + lane;                                                    \
    int m  = ch >> 3, p = ch & 7;                                             \
    int lc = p ^ (m & 7);                                                     \
    aoff[i] = (size_t)(m0 + m) * K + lc*8;                                    \
    boff[i] = (size_t)(n0 + m) * K + lc*8;                                    \
    ldsq[i] = qq * 1024;                                                      \
  }                                                                           \
  f32x4 acc[4][4];                                                            \
  const f32x4 vzero = {0.f,0.f,0.f,0.f};                                      \
  _Pragma("unroll")                                                           \
  for (int i = 0; i < 4; i++)                                                 \
    _Pragma("unroll")                                                         \
    for (int j = 0; j < 4; j++) acc[i][j] = vzero;                            \
  int arow[4], brow[4];                                                       \
  _Pragma("unroll")                                                           \
  for (int f = 0; f < 4; f++){                                                \
    arow[f] = (wm*64 + f*16 + (lane & 15)) * 64;                              \
    brow[f] = (wn*64 + f*16 + (lane & 15)) * 64;                              \
  }                                                                           \
  const int kg = lane >> 4;                                                   \
  const int l7 = lane & 7;

#define GEMM_STAGE(buf, kt)                                                   \
  _Pragma("unroll")                                                           \
  for (int i = 0; i < 4; i++){                                                \
    async_load16(Ae + aoff[i] + (kt)*64, (char*)&smem[(buf)*8192] + ldsq[i]); \
    async_load16(Be + boff[i] + (kt)*64, (char*)&smem[16384 + (buf)*8192] + ldsq[i]); \
  }

#define GEMM_COMPUTE(buf)                                                     \
  _Pragma("unroll")                                                           \
  for (int ks = 0; ks < 2; ks++){                                             \
    bf16x8 a[4], b[4];                                                        \
    const int pa = (ks*4 + kg) ^ l7;                                          \
    _Pragma("unroll")                                                         \
    for (int f = 0; f < 4; f++){                                              \
      a[f] = *(const bf16x8*)&smem[(buf)*8192 + arow[f] + pa*8];              \
      b[f] = *(const bf16x8*)&smem[16384 + (buf)*8192 + brow[f] + pa*8];      \
    }                                                                         \
    _Pragma("unroll")                                                         \
    for (int i = 0; i < 4; i++)                                               \
      _Pragma("unroll")                                                       \
      for (int j = 0; j < 4; j++)                                             \
        acc[i][j] = __builtin_amdgcn_mfma_f32_16x16x32_bf16(a[i], b[j], acc[i][j], 0, 0, 0); \
  }

#define GEMM_KLOOP(nkt)                                                       \
  GEMM_STAGE(0, 0);                                                           \
  __syncthreads();                                                            \
  int cur = 0;                                                                \
  for (int kt = 0; kt < (nkt); kt++){                                         \
    if (kt + 1 < (nkt)) { GEMM_STAGE(cur ^ 1, kt + 1); }                      \
    GEMM_COMPUTE(cur);                                                        \
    __syncthreads();                                                          \
    cur ^= 1;                                                                 \
  }

// mid logits split-K: Spart[b][i][j] = sum_{l in part} Q1T[b,i,l]*K1T[b,j,l]
__global__ __launch_bounds__(256) void gemm_mid(
    const unsigned short* __restrict__ A,
    const unsigned short* __restrict__ Bt,
    float* __restrict__ out0, float* __restrict__ out1)
{
  __shared__ unsigned short smem[32768];
  const int bid = blockIdx.x;
  const int wgid = (bid & 7) * 32 + (bid >> 3);    // 256 blocks
  const int part = wgid & 1;
  const int ntile = (wgid >> 1) & 3;
  const int mtile = (wgid >> 3) & 3;
  const int z = wgid >> 5;
  const int m0 = mtile * 128, n0 = ntile * 128;
  const int K = 4096;
  const unsigned short* Ae = A  + (size_t)z * 512 * 4096 + part * 2048;
  const unsigned short* Be = Bt + (size_t)z * 512 * 4096 + part * 2048;

  GEMM_PRE();
  GEMM_KLOOP(32);

  float* outf = part ? out1 : out0;
  const int lr = lane >> 4;
  const int lc16 = lane & 15;
  #pragma unroll
  for (int j = 0; j < 4; j++){
    int cidx = n0 + wn*64 + j*16 + lc16;
    #pragma unroll
    for (int i = 0; i < 4; i++){
      int r = m0 + wm*64 + i*16 + lr*4;
      #pragma unroll
      for (int q = 0; q < 4; q++)
        outf[(size_t)z * 262144 + (size_t)(r + q) * 512 + cidx] = acc[i][j][q];
    }
  }
}

// ===========================================================================
// 256x256-tile, 8-wave, 8-phase counted-vmcnt GEMM core (T2+T3+T4+T5)
// ===========================================================================
#define G8_PRE(AE)                                                            \
  const int t = threadIdx.x;                                                  \
  const int lane = t & 63;                                                    \
  const int wave = t >> 6;                                                    \
  const int wm = wave >> 2, wn = wave & 3;                                    \
  const int l15 = lane & 15, kg = lane >> 4;                                  \
  const int lcw = ((t & 7) ^ ((t >> 3) & 7)) * 8;                             \
  const unsigned short* a_src = (AE) + (size_t)(m0 + (t >> 3)) * 512 + lcw;   \
  f32x4 acc[8][4];                                                            \
  const f32x4 vzero = {0.f,0.f,0.f,0.f};                                      \
  _Pragma("unroll")                                                           \
  for (int i = 0; i < 8; i++)                                                 \
    _Pragma("unroll")                                                         \
    for (int j = 0; j < 4; j++) acc[i][j] = vzero;                            \
  bf16x8 af[4][2], bf[4][2];

#define STAGE_A(D,H,TT) do{                                                   \
  async_load16(a_src + (H)*65536 + (TT)*64,                                   \
               (char*)smem + ((D)*16384 + (H)*8192 + t*8)*2);                 \
  async_load16(a_src + (H)*65536 + 32768 + (TT)*64,                           \
               (char*)smem + ((D)*16384 + (H)*8192 + 4096 + t*8)*2);          \
}while(0)

#define STAGE_B(D,H,TT) do{                                                   \
  async_load16(b_src + (H)*bhoff + (TT)*64,                                   \
               (char*)smem + (32768 + (D)*16384 + (H)*8192 + t*8)*2);         \
  async_load16(b_src + (H)*bhoff + 32768 + (TT)*64,                           \
               (char*)smem + (32768 + (D)*16384 + (H)*8192 + 4096 + t*8)*2);  \
}while(0)

#define READ_A(D, MH) do{                                                     \
  _Pragma("unroll")                                                           \
  for (int mfl = 0; mfl < 4; ++mfl){                                          \
    const int rl = ((MH)*4 + mfl)*16 + l15;                                   \
    _Pragma("unroll")                                                         \
    for (int ks = 0; ks < 2; ++ks){                                           \
      const int ck = (ks*4 + kg) ^ (rl & 7);                                  \
      af[mfl][ks] = *(const bf16x8*)&smem[(D)*16384 + wm*8192 + rl*64 + ck*8];\
    }                                                                         \
  }                                                                           \
}while(0)

#define READ_B(D, NP) do{                                                     \
  _Pragma("unroll")                                                           \
  for (int nfl = 0; nfl < 2; ++nfl){                                          \
    const int nf = (NP)*2 + nfl;                                              \
    const int rbl = (wn & 1)*64 + nf*16 + l15;                                \
    _Pragma("unroll")                                                         \
    for (int ks = 0; ks < 2; ++ks){                                           \
      const int ck = (ks*4 + kg) ^ (rbl & 7);                                 \
      bf[nf][ks] = *(const bf16x8*)&smem[32768 + (D)*16384 + (wn>>1)*8192 + rbl*64 + ck*8]; \
    }                                                                         \
  }                                                                           \
}while(0)

#define QUAD(MH, NP)                                                          \
  _Pragma("unroll")                                                           \
  for (int mfl = 0; mfl < 4; ++mfl)                                           \
    _Pragma("unroll")                                                         \
    for (int nfl = 0; nfl < 2; ++nfl)                                         \
      _Pragma("unroll")                                                       \
      for (int ks = 0; ks < 2; ++ks)                                          \
        acc[(MH)*4+mfl][(NP)*2+nfl] = __builtin_amdgcn_mfma_f32_16x16x32_bf16(\
            af[mfl][ks], bf[(NP)*2+nfl][ks], acc[(MH)*4+mfl][(NP)*2+nfl], 0,0,0);

#define PH_MID()  CFENCE(); __builtin_amdgcn_s_barrier();                     \
  __builtin_amdgcn_s_setprio(1); SB0()
#define PH_END()  SB0(); __builtin_amdgcn_s_setprio(0); CFENCE();             \
  __builtin_amdgcn_s_barrier(); CFENCE()
#define PH_END_VM4() SB0(); __builtin_amdgcn_s_setprio(0);                    \
  asm volatile("s_waitcnt vmcnt(4)" ::: "memory");                            \
  __builtin_amdgcn_s_barrier(); CFENCE()
#define PH_END_VM0() SB0(); __builtin_amdgcn_s_setprio(0);                    \
  asm volatile("s_waitcnt vmcnt(0)" ::: "memory");                            \
  __builtin_amdgcn_s_barrier(); CFENCE()

// K = 512 fixed -> nkt = 8, niter = 4
#define G8_KLOOP()                                                            \
  STAGE_A(0,0,0); STAGE_A(0,1,0); STAGE_B(0,0,0); STAGE_B(0,1,0);             \
  STAGE_B(1,0,1); STAGE_B(1,1,1);                                             \
  asm volatile("s_waitcnt vmcnt(4)" ::: "memory");                            \
  __builtin_amdgcn_s_barrier(); CFENCE();                                     \
  for (int it = 0; it < 3; ++it){                                             \
    const int t1 = 2*it + 1, t2 = 2*it + 2, t3 = 2*it + 3;                    \
    READ_A(0,0); READ_B(0,0); STAGE_A(1,0,t1);                                \
    PH_MID(); QUAD(0,0); PH_END();                                            \
    READ_B(0,1); STAGE_A(1,1,t1);                                             \
    PH_MID(); QUAD(0,1); PH_END();                                            \
    READ_A(0,1); STAGE_B(0,0,t2);                                             \
    PH_MID(); QUAD(1,0); PH_END();                                            \
    STAGE_A(0,0,t2);                                                          \
    PH_MID(); QUAD(1,1); PH_END_VM4();                                        \
    READ_A(1,0); READ_B(1,0); STAGE_A(0,1,t2);                                \
    PH_MID(); QUAD(0,0); PH_END();                                            \
    READ_B(1,1); STAGE_B(0,1,t2);                                             \
    PH_MID(); QUAD(0,1); PH_END();                                            \
    READ_A(1,1); STAGE_B(1,0,t3);                                             \
    PH_MID(); QUAD(1,0); PH_END();                                            \
    STAGE_B(1,1,t3);                                                          \
    PH_MID(); QUAD(1,1); PH_END_VM4();                                        \
  }                                                                           \
  { /* last iteration: tiles 6 (dbuf0), 7 (dbuf1) */                          \
    READ_A(0,0); READ_B(0,0); STAGE_A(1,0,7);                                 \
    PH_MID(); QUAD(0,0); PH_END();                                            \
    READ_B(0,1); STAGE_A(1,1,7);                                              \
    PH_MID(); QUAD(0,1); PH_END();                                            \
    READ_A(0,1);                                                              \
    PH_MID(); QUAD(1,0); PH_END();                                            \
    PH_MID(); QUAD(1,1); PH_END_VM0();                                        \
    READ_A(1,0); READ_B(1,0);                                                 \
    PH_MID(); QUAD(0,0); PH_END();                                            \
    READ_B(1,1);                                                              \
    PH_MID(); QUAD(0,1); PH_END();                                            \
    READ_A(1,1);                                                              \
    PH_MID(); QUAD(1,0); PH_END();                                            \
    PH_MID(); QUAD(1,1); PH_END();                                            \
  }

// ---------------------------------------------------------------------------
// fused projection: per mtile, 10 nslots:
//  0,1  Q cols [0,256),[256,512)  -> relu, write Qb
//  2..5 KV pair p=nslot-2: K & V cols [p*128,(p+1)*128) -> in-LDS K exchange,
//       atomicAdd Ksum (K-waves) and diagKV (V-waves); NO global tile write
//  6,7  Q1 -> transposed write to Q1T
//  8,9  K1 -> transposed write to K1T
__global__ __launch_bounds__(512, 2) void gemm8_proj(
    const unsigned short* __restrict__ A,
    const unsigned short* __restrict__ W,
    const float* __restrict__ bias5,
    unsigned short* __restrict__ Qb,
    unsigned short* __restrict__ Q1T, unsigned short* __restrict__ K1T,
    float* __restrict__ diag, float* __restrict__ ksum)
{
  __shared__ unsigned short smem[65536];   // 128KB
  const int bid = blockIdx.x;
  const int wgid = (bid & 7) * 160 + (bid >> 3);   // 1280 % 8 == 0: bijective
  const int mtile = wgid / 10;
  const int nslot = wgid % 10;
  const int m0 = mtile * 256;

  int mode, wsel = 0, nbase = 0, p = 0;
  if (nslot < 2)      { mode = 0; wsel = 0; nbase = nslot * 256; }
  else if (nslot < 6) { mode = 1; p = nslot - 2; }
  else if (nslot < 8) { mode = 2; wsel = 3; nbase = (nslot - 6) * 256; }
  else                { mode = 3; wsel = 4; nbase = (nslot - 8) * 256; }

  G8_PRE(A);
  const unsigned short* b_src; int bhoff;
  if (mode == 1){
    b_src = W + 262144 + (size_t)(p*128 + (t >> 3)) * 512 + lcw;   // Wk panel
    bhoff = 262144;                                                 // +H -> Wv
  } else {
    b_src = W + (size_t)wsel * 262144 + (size_t)(nbase + (t >> 3)) * 512 + lcw;
    bhoff = 65536;
  }

  G8_KLOOP();

  if (mode == 0){
    // Q: coalesced epilogue via LDS
    __syncthreads();
    #pragma unroll
    for (int nf = 0; nf < 4; nf++){
      int cl = wn*64 + nf*16 + l15;
      float bb = bias5[nbase + cl];
      #pragma unroll
      for (int mf = 0; mf < 8; mf++){
        int rbase = wm*128 + mf*16 + kg*4;
        #pragma unroll
        for (int q = 0; q < 4; q++){
          float v = acc[mf][nf][q] + bb;
          v = v > 0.f ? v : 0.f;
          int rl = rbase + q;
          smem[rl*256 + (cl ^ (((rl >> 2) & 3) << 4))] = f2bf(v);
        }
      }
    }
    __syncthreads();
    const int c0 = (t & 31) * 8;
    #pragma unroll
    for (int rep = 0; rep < 16; rep++){
      int rl = rep*16 + (t >> 5);
      bf16x8 v = *(const bf16x8*)&smem[rl*256 + (c0 ^ (((rl >> 2) & 3) << 4))];
      *(bf16x8*)(Qb + (size_t)(m0 + rl) * 512 + nbase + c0) = v;
    }
  } else if (mode == 1){
    // KV exchange: K-waves (wn<2) write relu'd K to LDS + Ksum atomics;
    // V-waves (wn>=2) read K, multiply with V, diagKV atomics.
    const int b = mtile >> 4;
    __syncthreads();
    if (wn < 2){
      #pragma unroll
      for (int nf = 0; nf < 4; nf++){
        int cl = (wn & 1)*64 + nf*16 + l15;         // col within 128-panel
        float bb = bias5[512 + p*128 + cl];
        float ks_ = 0.f;
        #pragma unroll
        for (int mf = 0; mf < 8; mf++){
          int rbase = wm*128 + mf*16 + kg*4;
          #pragma unroll
          for (int q = 0; q < 4; q++){
            float v = acc[mf][nf][q] + bb;
            v = v > 0.f ? v : 0.f;
            unsigned short h = f2bf(v);
            int r = rbase + q;
            smem[r*128 + (cl ^ (((r >> 2) & 7) << 4))] = h;
            ks_ += bf2f(h);
          }
        }
        ks_ += __shfl_xor(ks_, 16);
        ks_ += __shfl_xor(ks_, 32);
        if (kg == 0) atomicAdd(&ksum[b*512 + p*128 + cl], ks_);
      }
    }
    __syncthreads();
    if (wn >= 2){
      #pragma unroll
      for (int nf = 0; nf < 4; nf++){
        int cl = (wn & 1)*64 + nf*16 + l15;
        float bb = bias5[1024 + p*128 + cl];
        float dv = 0.f;
        #pragma unroll
        for (int mf = 0; mf < 8; mf++){
          int rbase = wm*128 + mf*16 + kg*4;
          #pragma unroll
          for (int q = 0; q < 4; q++){
            int r = rbase + q;
            float kf = bf2f(smem[r*128 + (cl ^ (((r >> 2) & 7) << 4))]);
            float vf = bf2f(f2bf(acc[mf][nf][q] + bb));
            dv += kf * vf;
          }
        }
        dv += __shfl_xor(dv, 16);
        dv += __shfl_xor(dv, 32);
        if (kg == 0) atomicAdd(&diag[b*512 + p*128 + cl], dv);
      }
    }
  } else {
    // Q1/K1: transposed output via in-LDS 256x256 transpose
    unsigned short* o = (mode == 2) ? Q1T : K1T;
    const int b = mtile >> 4;
    const int l0 = (mtile & 15) * 256;
    __syncthreads();
    #pragma unroll
    for (int nf = 0; nf < 4; nf++){
      int cl_ = wn*64 + nf*16 + l15;
      float bb = bias5[wsel*512 + nbase + cl_];
      #pragma unroll
      for (int mf = 0; mf < 8; mf++){
        #pragma unroll
        for (int q = 0; q < 4; q++){
          int ll = wm*128 + mf*16 + kg*4 + q;
          int sw = ((ll >> 3) ^ (cl_ & 7)) * 8 + (ll & 7);
          smem[cl_*256 + sw] = f2bf(acc[mf][nf][q] + bb);
        }
      }
    }
    __syncthreads();
    #pragma unroll
    for (int rep = 0; rep < 16; rep++){
      int c = rep*16 + (t >> 5);
      int lch = t & 31;
      bf16x8 v = *(const bf16x8*)&smem[c*256 + (lch ^ (c & 7))*8];
      *(bf16x8*)(o + ((size_t)b*512 + nbase + c)*4096 + l0 + lch*8) = v;
    }
  }
}

// ---------------------------------------------------------------------------
// result GEMM: y = xs + gamma*Z[l]*(Q @ midT'^T) in-place + BN stats.
// midT' rows already scaled by diagKV. grid = 256 x 512 threads.
__global__ __launch_bounds__(512, 2) void gemm8_res(
    const unsigned short* __restrict__ A,        // Qb [32768][512]
    const unsigned short* __restrict__ Bt,       // midT' [8][512][512]
    const float* __restrict__ Zp,                // [32768]
    unsigned short* __restrict__ outh,           // xs bf16, in-place -> y
    const float* __restrict__ gamma_p,
    float* __restrict__ bnS, float* __restrict__ bnQ)
{
  __shared__ unsigned short smem[65536];
  __shared__ float zbuf[256];
  const int bid = blockIdx.x;
  const int wgid = (bid & 7) * 32 + (bid >> 3);   // 256 % 8 == 0
  const int mtile = wgid >> 1;
  const int ntile = wgid & 1;
  const int m0 = mtile * 256;
  const int nc0 = ntile * 256;

  G8_PRE(A);
  const unsigned short* b_src =
      Bt + (size_t)(mtile >> 4) * 262144 + (size_t)(nc0 + (t >> 3)) * 512 + lcw;
  const int bhoff = 65536;

  G8_KLOOP();

  const float g = gamma_p[0];
  __syncthreads();
  if (t < 256) zbuf[t] = Zp[m0 + t];
  __syncthreads();
  // stage 1: g*Z*acc -> LDS bf16 swizzled
  #pragma unroll
  for (int nf = 0; nf < 4; nf++){
    int cl = wn*64 + nf*16 + l15;
    #pragma unroll
    for (int mf = 0; mf < 8; mf++){
      int rbase = wm*128 + mf*16 + kg*4;
      #pragma unroll
      for (int q = 0; q < 4; q++){
        int rl = rbase + q;
        smem[rl*256 + (cl ^ (((rl >> 2) & 3) << 4))] =
            f2bf(g * zbuf[rl] * acc[mf][nf][q]);
      }
    }
  }
  __syncthreads();
  // stage 2: coalesced RMW + per-thread col partials
  float sc[8] = {0.f,0.f,0.f,0.f,0.f,0.f,0.f,0.f};
  float sq[8] = {0.f,0.f,0.f,0.f,0.f,0.f,0.f,0.f};
  const int c0 = (t & 31) * 8;
  #pragma unroll
  for (int rep = 0; rep < 16; rep++){
    int rl = rep*16 + (t >> 5);
    bf16x8 ga = *(const bf16x8*)&smem[rl*256 + (c0 ^ (((rl >> 2) & 3) << 4))];
    size_t gidx = (size_t)(m0 + rl) * 512 + nc0 + c0;
    bf16x8 xv = *(const bf16x8*)(outh + gidx);
    bf16x8 yv;
    #pragma unroll
    for (int j = 0; j < 8; j++){
      float y = bf2f((unsigned short)xv[j]) + bf2f((unsigned short)ga[j]);
      yv[j] = (short)f2bf(y);
      sc[j] += y; sq[j] += y * y;
    }
    *(bf16x8*)(outh + gidx) = yv;
  }
  __syncthreads();
  // stage 3: reduce col partials across 16 row-groups, then atomics
  float* red = (float*)(void*)smem;
  const int tg = t >> 5;
  f32x4 s0 = {sc[0],sc[1],sc[2],sc[3]}, s1 = {sc[4],sc[5],sc[6],sc[7]};
  f32x4 q0 = {sq[0],sq[1],sq[2],sq[3]}, q1 = {sq[4],sq[5],sq[6],sq[7]};
  *(f32x4*)&red[tg*256 + c0]        = s0;  *(f32x4*)&red[tg*256 + c0 + 4]        = s1;
  *(f32x4*)&red[4096 + tg*256 + c0] = q0;  *(f32x4*)&red[4096 + tg*256 + c0 + 4] = q1;
  __syncthreads();
  if (t < 256){
    float ss = 0.f, qq = 0.f;
    #pragma unroll
    for (int gg = 0; gg < 16; gg++){
      ss += red[gg*256 + t];
      qq += red[4096 + gg*256 + t];
    }
    atomicAdd(&bnS[nc0 + t], ss);
    atomicAdd(&bnQ[nc0 + t], qq);
  }
}

// ---------------------------------------------------------------------------
// finalize: y[b][l][c] bf16 -> out[b][c][l] fp32, BN affine + relu
__global__ __launch_bounds__(256) void k_bn_finalize(
    const unsigned short* __restrict__ y, const float* __restrict__ bnS,
    const float* __restrict__ bnQ, const float* __restrict__ bnw,
    const float* __restrict__ bnb, float* __restrict__ out)
{
  __shared__ float tile[64][65];
  __shared__ float scale_s[64], shift_s[64];
  const int lt = blockIdx.x, ct = blockIdx.y, b = blockIdx.z;
  const int t = threadIdx.x;
  if (t < 64){
    int c = ct*64 + t;
    float s = bnS[c], q = bnQ[c];
    float mean = s * (1.0f / 32768.0f);
    float var  = q * (1.0f / 32768.0f) - mean * mean;
    float inv  = rsqrtf(var + 1e-5f);
    float scv  = bnw[c] * inv;
    scale_s[t] = scv;
    shift_s[t] = bnb[c] - mean * scv;
  }
  const int rr = t >> 3, c8 = (t & 7) * 8;
  #pragma unroll
  for (int pass = 0; pass < 2; pass++){
    int l = rr + pass * 32;
    bf16x8 v = *(const bf16x8*)(y + ((size_t)b * 4096 + lt*64 + l) * 512 + ct*64 + c8);
    #pragma unroll
    for (int s = 0; s < 8; s++) tile[l][c8+s] = bf2f((unsigned short)v[s]);
  }
  __syncthreads();
  #pragma unroll
  for (int pass = 0; pass < 2; pass++){
    int c = rr + pass * 32;
    float scv = scale_s[c], sh = shift_s[c];
    f32x4 o0, o1;
    #pragma unroll
    for (int s = 0; s < 4; s++){
      float v = tile[c8+s][c] * scv + sh;     o0[s] = v > 0.f ? v : 0.f;
      float w = tile[c8+4+s][c] * scv + sh;   o1[s] = w > 0.f ? w : 0.f;
    }
    float* dp = out + ((size_t)b * 512 + ct*64 + c) * 4096 + lt*64 + c8;
    *(f32x4*)dp = o0;
    *(f32x4*)(dp + 4) = o1;
  }
}

// ---------------------------------------------------------------------------
extern "C" void kernel_launch(void* const* d_in, const int* in_sizes, int n_in,
                              void* d_out, int out_size, void* d_ws, size_t ws_size,
                              hipStream_t stream)
{
  const float* x    = (const float*)d_in[0];
  const float* pos  = (const float*)d_in[1];
  const float* Wq   = (const float*)d_in[2];
  const float* bq   = (const float*)d_in[3];
  const float* Wk   = (const float*)d_in[4];
  const float* bk   = (const float*)d_in[5];
  const float* Wv   = (const float*)d_in[6];
  const float* bv   = (const float*)d_in[7];
  const float* Wq1  = (const float*)d_in[8];
  const float* bq1  = (const float*)d_in[9];
  const float* Wk1  = (const float*)d_in[10];
  const float* bk1  = (const float*)d_in[11];
  const float* gam  = (const float*)d_in[12];
  const float* bnw  = (const float*)d_in[13];
  const float* bnb  = (const float*)d_in[14];
  float* out = (float*)d_out;
  char* ws = (char*)d_ws;

  const size_t MB = 1ull << 20;
  const size_t OFF_XSB  = 0;                  // 32MB xs_bf -> y in-place
  const size_t OFF_QB   = 32*MB;              // 32MB Q
  const size_t OFF_Q1T  = 64*MB;              // 32MB Q1^T [8][512][4096]
  const size_t OFF_K1T  = 96*MB;              // 32MB K1^T
  const size_t OFF_SF0  = 128*MB;             // 8MB  S part0 fp32
  const size_t OFF_SF1  = 136*MB;             // 8MB  S part1 fp32
  const size_t OFF_MIDB = 144*MB;             // 4MB  mid bf16
  const size_t OFF_MIDT = 148*MB;             // 4MB  midT' bf16 (diag-scaled)
  const size_t OFF_WBF  = 152*MB;             // 2.5MB
  const size_t OFF_B5   = 155*MB;             // 10KB
  const size_t OFF_Z    = 156*MB;             // 128KB fp32
  const size_t OFF_DIAG = 157*MB;
  const size_t OFF_KSUM = OFF_DIAG + 16384;
  const size_t OFF_BNS  = OFF_KSUM + 16384;
  const size_t OFF_BNQ  = OFF_BNS + 2048;
  const size_t WS_NEED  = OFF_BNQ + 2048;
  if (ws_size < WS_NEED) return;

  unsigned short* xsb  = (unsigned short*)(ws + OFF_XSB);
  unsigned short* Qb   = (unsigned short*)(ws + OFF_QB);
  unsigned short* Q1T  = (unsigned short*)(ws + OFF_Q1T);
  unsigned short* K1T  = (unsigned short*)(ws + OFF_K1T);
  float*          Sf0  = (float*)(ws + OFF_SF0);
  float*          Sf1  = (float*)(ws + OFF_SF1);
  unsigned short* midb = (unsigned short*)(ws + OFF_MIDB);
  unsigned short* midT = (unsigned short*)(ws + OFF_MIDT);
  unsigned short* wbf  = (unsigned short*)(ws + OFF_WBF);
  float* bias5 = (float*)(ws + OFF_B5);
  float* Zp   = (float*)(ws + OFF_Z);
  float* diag = (float*)(ws + OFF_DIAG);
  float* ksum = (float*)(ws + OFF_KSUM);
  float* bnS  = (float*)(ws + OFF_BNS);
  float* bnQ  = (float*)(ws + OFF_BNQ);

  hipMemsetAsync(ws + OFF_DIAG, 0, 16384 + 16384 + 2048 + 2048, stream);

  k_prep_w  <<<dim3(1024, 5), 256, 0, stream>>>(Wq, Wk, Wv, Wq1, Wk1, wbf);
  k_prep_b  <<<dim3(10),      256, 0, stream>>>(bq, bk, bv, bq1, bk1, bias5);
  k_build_xs<<<dim3(64, 8, 8),256, 0, stream>>>(x, pos, xsb);

  // fused projections: writes Qb, Q1T, K1T; accumulates diagKV/Ksum in-kernel
  gemm8_proj<<<dim3(1280), 512, 0, stream>>>(xsb, wbf, bias5, Qb, Q1T, K1T, diag, ksum);

  // Z row-normalizer (reads Q + Ksum)
  k_z<<<dim3(8192), 256, 0, stream>>>(Qb, ksum, Zp);

  // mid logits split-K over l (2 parts, 256 blocks)
  gemm_mid<<<dim3(256), 256, 0, stream>>>(Q1T, K1T, Sf0, Sf1);

  k_softmax<<<dim3(4096), 64, 0, stream>>>(Sf0, Sf1, midb);

  // transpose mid with diagKV row-scale fold
  k_transpose_scale<<<dim3(8, 8, 8), 256, 0, stream>>>(midb, diag, midT);

  // result GEMM + residual + BN-stat epilogue (y in-place over xs_bf)
  gemm8_res<<<dim3(256), 512, 0, stream>>>(Qb, midT, Zp, xsb, gam, bnS, bnQ);

  k_bn_finalize<<<dim3(64, 8, 8), 256, 0, stream>>>(xsb, bnS, bnQ, bnw, bnb, out);
}